// Round 3
// baseline (1826.543 us; speedup 1.0000x reference)
//
#include <hip/hip_runtime.h>

#define D 128

typedef float nfloat4 __attribute__((ext_vector_type(4)));

__device__ __forceinline__ void nt_store_f4(const float4& v, float4* p) {
    nfloat4 nv;
    nv.x = v.x; nv.y = v.y; nv.z = v.z; nv.w = v.w;
    __builtin_nontemporal_store(nv, reinterpret_cast<nfloat4*>(p));
}

// ---------------- int degree histogram ----------------
__global__ void k_deg(const int* __restrict__ dst, int* __restrict__ deg, int E) {
    int e = blockIdx.x * blockDim.x + threadIdx.x;
    if (e < E) atomicAdd(&deg[dst[e]], 1);
}

// ---------------- single-block exclusive scan (rowptr) ----------------
__global__ __launch_bounds__(1024) void k_scan(const int* __restrict__ deg,
                                               int* __restrict__ rowptr, int N) {
    __shared__ int wsum[16];
    __shared__ int wscan[16];
    __shared__ int s_carry;
    const int tid = threadIdx.x, lane = tid & 63, wid = tid >> 6;
    if (tid == 0) s_carry = 0;
    __syncthreads();
    for (int base = 0; base < N; base += 1024) {
        int i = base + tid;
        int v = (i < N) ? deg[i] : 0;
        int x = v;
        #pragma unroll
        for (int off = 1; off < 64; off <<= 1) {
            int t = __shfl_up(x, off);
            if (lane >= off) x += t;
        }
        if (lane == 63) wsum[wid] = x;
        __syncthreads();
        if (wid == 0) {
            int s = (lane < 16) ? wsum[lane] : 0;
            #pragma unroll
            for (int off = 1; off < 16; off <<= 1) {
                int t = __shfl_up(s, off);
                if (lane >= off) s += t;
            }
            if (lane < 16) wscan[lane] = s;
        }
        __syncthreads();
        int woff = (wid > 0) ? wscan[wid - 1] : 0;
        int incl = x + woff;
        int carry = s_carry;
        if (i < N) rowptr[i] = carry + incl - v;
        __syncthreads();
        if (tid == 1023) s_carry = carry + wscan[15];
        __syncthreads();
    }
    if (threadIdx.x == 0) rowptr[N] = s_carry;
}

// ---------------- CSR fill (cursor pre-seeded with rowptr) ----------------
__global__ void k_fill(const int* __restrict__ src, const int* __restrict__ dst,
                       int* __restrict__ cursor, int* __restrict__ csr, int E) {
    int e = blockIdx.x * blockDim.x + threadIdx.x;
    if (e >= E) return;
    int d = dst[e];
    int pos = atomicAdd(&cursor[d], 1);
    csr[pos] = src[e];
}

// ---------------- gather-mean aggregation ----------------
// One wave per dst node. Half-wave per source row: lanes 0-31 row a (float4 each,
// 16B/lane), lanes 32-63 row b. 4 chains -> 8 edges / 4KB in flight per wave.
__global__ __launch_bounds__(256) void k_agg(const int* __restrict__ rowptr,
                                             const int* __restrict__ csr,
                                             const float* __restrict__ xin,
                                             float* __restrict__ agg, int N) {
    int w = (int)((blockIdx.x * 256u + threadIdx.x) >> 6);
    int lane = threadIdx.x & 63;
    if (w >= N) return;
    int s0 = rowptr[w], s1 = rowptr[w + 1];
    const int half = lane >> 5;
    const int c4 = lane & 31;                 // float4 index within row
    const float4* xin4 = reinterpret_cast<const float4*>(xin);
    float4 a0 = make_float4(0.f, 0.f, 0.f, 0.f);
    float4 a1 = make_float4(0.f, 0.f, 0.f, 0.f);
    float4 a2 = make_float4(0.f, 0.f, 0.f, 0.f);
    float4 a3 = make_float4(0.f, 0.f, 0.f, 0.f);

    for (int p = s0; p < s1; p += 64) {
        int m = s1 - p; if (m > 64) m = 64;
        int my = (p + lane < s1) ? csr[p + lane] : 0;
        int j = 0;
        for (; j + 7 < m; j += 8) {
            int r0 = __shfl(my, j + half);
            int r1 = __shfl(my, j + 2 + half);
            int r2 = __shfl(my, j + 4 + half);
            int r3 = __shfl(my, j + 6 + half);
            float4 v0 = xin4[(size_t)r0 * 32 + c4];
            float4 v1 = xin4[(size_t)r1 * 32 + c4];
            float4 v2 = xin4[(size_t)r2 * 32 + c4];
            float4 v3 = xin4[(size_t)r3 * 32 + c4];
            a0.x += v0.x; a0.y += v0.y; a0.z += v0.z; a0.w += v0.w;
            a1.x += v1.x; a1.y += v1.y; a1.z += v1.z; a1.w += v1.w;
            a2.x += v2.x; a2.y += v2.y; a2.z += v2.z; a2.w += v2.w;
            a3.x += v3.x; a3.y += v3.y; a3.z += v3.z; a3.w += v3.w;
        }
        for (; j + 1 < m; j += 2) {
            int r0 = __shfl(my, j + half);
            float4 v0 = xin4[(size_t)r0 * 32 + c4];
            a0.x += v0.x; a0.y += v0.y; a0.z += v0.z; a0.w += v0.w;
        }
        if (j < m) {
            int r0 = __shfl(my, j);
            float4 v0 = xin4[(size_t)r0 * 32 + c4];
            if (half == 0) {
                a0.x += v0.x; a0.y += v0.y; a0.z += v0.z; a0.w += v0.w;
            }
        }
    }

    float4 s;
    s.x = (a0.x + a1.x) + (a2.x + a3.x);
    s.y = (a0.y + a1.y) + (a2.y + a3.y);
    s.z = (a0.z + a1.z) + (a2.z + a3.z);
    s.w = (a0.w + a1.w) + (a2.w + a3.w);
    s.x += __shfl_xor(s.x, 32);
    s.y += __shfl_xor(s.y, 32);
    s.z += __shfl_xor(s.z, 32);
    s.w += __shfl_xor(s.w, 32);

    float inv = 1.0f / fmaxf((float)(s1 - s0), 1.0f);
    if (half == 0) {
        float4 o = make_float4(s.x * inv, s.y * inv, s.z * inv, s.w * inv);
        nt_store_f4(o, &reinterpret_cast<float4*>(agg)[(size_t)w * 32 + c4]);
    }
}

// ---------------- register-tiled SGEMM with reg-staged prefetch (T14) ----------------
// out[i,j] = act( sum_m sum_k A_m[i,k] * W_m[j,k] + bias[j] )
template <bool RELU, int NMAT, bool NT>
__global__ __launch_bounds__(256) void k_gemm(
    const float* __restrict__ A0, const float* __restrict__ A1,
    const float* __restrict__ W0, const float* __restrict__ W1,
    const float* __restrict__ bias,
    float* __restrict__ out, int N)
{
    __shared__ float sA[128 * 36];   // rows x (BK=32 + pad4)
    __shared__ float sW[32 * 132];   // k x (128 cols + pad4)

    const int tid = threadIdx.x;
    const int tx  = tid & 15;
    const int ty  = tid >> 4;
    const int base = blockIdx.x * 128;

    float acc[2][2][4][4];
    #pragma unroll
    for (int a = 0; a < 2; ++a)
        #pragma unroll
        for (int b = 0; b < 2; ++b)
            #pragma unroll
            for (int i = 0; i < 4; ++i)
                #pragma unroll
                for (int j = 0; j < 4; ++j)
                    acc[a][b][i][j] = 0.0f;

    float4 regA[4], regW[4];

    auto load_regs = [&](int c) {
        const float* Asrc = (NMAT == 2 && c >= 4) ? A1 : A0;
        const float* Wsrc = (NMAT == 2 && c >= 4) ? W1 : W0;
        const int kc = (c & 3) * 32;
        #pragma unroll
        for (int it = 0; it < 4; ++it) {
            int row = it * 32 + (tid >> 3);
            int grow = base + row; if (grow >= N) grow = N - 1;
            regA[it] = *reinterpret_cast<const float4*>(
                &Asrc[(size_t)grow * D + kc + (tid & 7) * 4]);
            regW[it] = *reinterpret_cast<const float4*>(
                &Wsrc[(size_t)row * D + kc + (tid & 7) * 4]);
        }
    };
    auto write_lds = [&]() {
        #pragma unroll
        for (int it = 0; it < 4; ++it) {
            int row = it * 32 + (tid >> 3);       // A-row / W-output-col
            int k0  = (tid & 7) * 4;
            *reinterpret_cast<float4*>(&sA[row * 36 + k0]) = regA[it];
            sW[(k0 + 0) * 132 + row] = regW[it].x;
            sW[(k0 + 1) * 132 + row] = regW[it].y;
            sW[(k0 + 2) * 132 + row] = regW[it].z;
            sW[(k0 + 3) * 132 + row] = regW[it].w;
        }
    };
    auto compute = [&]() {
        #pragma unroll
        for (int kk = 0; kk < 32; kk += 4) {
            float4 av[2][4];
            #pragma unroll
            for (int rh = 0; rh < 2; ++rh)
                #pragma unroll
                for (int ri = 0; ri < 4; ++ri)
                    av[rh][ri] = *reinterpret_cast<const float4*>(
                        &sA[(rh * 64 + ty * 4 + ri) * 36 + kk]);
            float4 wv[4][2];
            #pragma unroll
            for (int kq = 0; kq < 4; ++kq)
                #pragma unroll
                for (int c = 0; c < 2; ++c)
                    wv[kq][c] = *reinterpret_cast<const float4*>(
                        &sW[(kk + kq) * 132 + c * 64 + tx * 4]);
            #pragma unroll
            for (int kq = 0; kq < 4; ++kq) {
                #pragma unroll
                for (int rh = 0; rh < 2; ++rh) {
                    #pragma unroll
                    for (int ri = 0; ri < 4; ++ri) {
                        float a = reinterpret_cast<const float*>(&av[rh][ri])[kq];
                        #pragma unroll
                        for (int c = 0; c < 2; ++c) {
                            float4 w = wv[kq][c];
                            acc[rh][c][ri][0] = fmaf(a, w.x, acc[rh][c][ri][0]);
                            acc[rh][c][ri][1] = fmaf(a, w.y, acc[rh][c][ri][1]);
                            acc[rh][c][ri][2] = fmaf(a, w.z, acc[rh][c][ri][2]);
                            acc[rh][c][ri][3] = fmaf(a, w.w, acc[rh][c][ri][3]);
                        }
                    }
                }
            }
        }
    };

    const int NCH = NMAT * 4;
    load_regs(0);
    write_lds();
    __syncthreads();
    for (int c = 0; c < NCH; ++c) {
        if (c + 1 < NCH) load_regs(c + 1);   // issue next chunk's global loads early
        compute();                            // latency hides under 32-k FMA block
        __syncthreads();                      // all waves done reading this chunk
        if (c + 1 < NCH) { write_lds(); __syncthreads(); }
    }

    // epilogue: bias + activation + store
    float4 b4[2];
    b4[0] = *reinterpret_cast<const float4*>(&bias[tx * 4]);
    b4[1] = *reinterpret_cast<const float4*>(&bias[64 + tx * 4]);
    #pragma unroll
    for (int rh = 0; rh < 2; ++rh) {
        #pragma unroll
        for (int ri = 0; ri < 4; ++ri) {
            int row = base + rh * 64 + ty * 4 + ri;
            if (row < N) {
                #pragma unroll
                for (int c = 0; c < 2; ++c) {
                    float4 o;
                    o.x = acc[rh][c][ri][0] + b4[c].x;
                    o.y = acc[rh][c][ri][1] + b4[c].y;
                    o.z = acc[rh][c][ri][2] + b4[c].z;
                    o.w = acc[rh][c][ri][3] + b4[c].w;
                    if (RELU) {
                        o.x = fmaxf(o.x, 0.0f); o.y = fmaxf(o.y, 0.0f);
                        o.z = fmaxf(o.z, 0.0f); o.w = fmaxf(o.w, 0.0f);
                    }
                    float4* dst = reinterpret_cast<float4*>(
                        &out[(size_t)row * D + c * 64 + tx * 4]);
                    if (NT) nt_store_f4(o, dst);
                    else    *dst = o;
                }
            }
        }
    }
}

extern "C" void kernel_launch(void* const* d_in, const int* in_sizes, int n_in,
                              void* d_out, int out_size, void* d_ws, size_t ws_size,
                              hipStream_t stream) {
    const float* x   = (const float*)d_in[0];
    const int*   ei  = (const int*)d_in[1];
    const float* Wl0 = (const float*)d_in[2];
    const float* bl0 = (const float*)d_in[3];
    const float* Wr0 = (const float*)d_in[4];
    const float* Wl1 = (const float*)d_in[5];
    const float* bl1 = (const float*)d_in[6];
    const float* Wr1 = (const float*)d_in[7];
    const float* Wv  = (const float*)d_in[8];
    const float* bv  = (const float*)d_in[9];
    const float* Wt  = (const float*)d_in[10];
    const float* bt  = (const float*)d_in[11];

    const int N = in_sizes[0] / D;       // 100000
    const int E = in_sizes[1] / 2;       // 1600000
    const int* srcv = ei;
    const int* dstv = ei + E;

    float* out  = (float*)d_out;
    float* h    = out;                        // [0, N*D)      final output 0
    float* h1   = out + (size_t)N * D;        // scratch, later x_vision
    float* aggb = out + 2 * (size_t)N * D;    // scratch, later x_text

    // CSR workspace: deg(N) | rowptr(N+1) | cursor(N) | csr(E)  — ints
    size_t need = ((size_t)(3 * N + 1) + (size_t)E) * sizeof(int);
    int* wsI = (ws_size >= need) ? (int*)d_ws
                                 : (int*)h;   // fallback: h region is free until layer-1 gemm
    int* degI   = wsI;
    int* rowptr = wsI + N;
    int* cursor = wsI + 2 * N + 1;
    int* csr    = wsI + 2 * N + 1 + N;

    (void)hipMemsetAsync(degI, 0, (size_t)N * sizeof(int), stream);
    k_deg <<<(E + 255) / 256, 256, 0, stream>>>(dstv, degI, E);
    k_scan<<<1, 1024, 0, stream>>>(degI, rowptr, N);
    (void)hipMemcpyAsync(cursor, rowptr, (size_t)N * sizeof(int),
                         hipMemcpyDeviceToDevice, stream);
    k_fill<<<(E + 255) / 256, 256, 0, stream>>>(srcv, dstv, cursor, csr, E);

    const int agg_blocks  = (int)(((size_t)N * 64 + 255) / 256);
    const int gemm_blocks = (N + 127) / 128;

    // ---- layer 0 ----
    k_agg<<<agg_blocks, 256, 0, stream>>>(rowptr, csr, x, aggb, N);
    k_gemm<true, 2, false><<<gemm_blocks, 256, 0, stream>>>(aggb, x, Wl0, Wr0, bl0, h1, N);

    // ---- layer 1 ----
    k_agg<<<agg_blocks, 256, 0, stream>>>(rowptr, csr, h1, aggb, N);
    k_gemm<false, 2, false><<<gemm_blocks, 256, 0, stream>>>(aggb, h1, Wl1, Wr1, bl1, h, N);

    // ---- heads: xv = relu(h@Wv^T+bv), xt = relu(h@Wt^T+bt) ----
    k_gemm<true, 1, true><<<gemm_blocks, 256, 0, stream>>>(h, nullptr, Wv, nullptr, bv,
                                                           out + (size_t)N * D, N);
    k_gemm<true, 1, true><<<gemm_blocks, 256, 0, stream>>>(h, nullptr, Wt, nullptr, bt,
                                                           out + 2 * (size_t)N * D, N);
}

// Round 4
// 812.645 us; speedup vs baseline: 2.2477x; 2.2477x over previous
//
#include <hip/hip_runtime.h>

#define D 128

typedef float nfloat4 __attribute__((ext_vector_type(4)));

__device__ __forceinline__ void nt_store_f4(const float4& v, float4* p) {
    nfloat4 nv;
    nv.x = v.x; nv.y = v.y; nv.z = v.z; nv.w = v.w;
    __builtin_nontemporal_store(nv, reinterpret_cast<nfloat4*>(p));
}

// ---------------- int degree histogram ----------------
__global__ void k_deg(const int* __restrict__ dst, int* __restrict__ deg, int E) {
    int e = blockIdx.x * blockDim.x + threadIdx.x;
    if (e < E) atomicAdd(&deg[dst[e]], 1);
}

// ---------------- single-block exclusive scan (rowptr) ----------------
__global__ __launch_bounds__(1024) void k_scan(const int* __restrict__ deg,
                                               int* __restrict__ rowptr, int N) {
    __shared__ int wsum[16];
    __shared__ int wscan[16];
    __shared__ int s_carry;
    const int tid = threadIdx.x, lane = tid & 63, wid = tid >> 6;
    if (tid == 0) s_carry = 0;
    __syncthreads();
    for (int base = 0; base < N; base += 1024) {
        int i = base + tid;
        int v = (i < N) ? deg[i] : 0;
        int x = v;
        #pragma unroll
        for (int off = 1; off < 64; off <<= 1) {
            int t = __shfl_up(x, off);
            if (lane >= off) x += t;
        }
        if (lane == 63) wsum[wid] = x;
        __syncthreads();
        if (wid == 0) {
            int s = (lane < 16) ? wsum[lane] : 0;
            #pragma unroll
            for (int off = 1; off < 16; off <<= 1) {
                int t = __shfl_up(s, off);
                if (lane >= off) s += t;
            }
            if (lane < 16) wscan[lane] = s;
        }
        __syncthreads();
        int woff = (wid > 0) ? wscan[wid - 1] : 0;
        int incl = x + woff;
        int carry = s_carry;
        if (i < N) rowptr[i] = carry + incl - v;
        __syncthreads();
        if (tid == 1023) s_carry = carry + wscan[15];
        __syncthreads();
    }
    if (threadIdx.x == 0) rowptr[N] = s_carry;
}

// ---------------- CSR fill (cursor pre-seeded with rowptr) ----------------
__global__ void k_fill(const int* __restrict__ src, const int* __restrict__ dst,
                       int* __restrict__ cursor, int* __restrict__ csr, int E) {
    int e = blockIdx.x * blockDim.x + threadIdx.x;
    if (e >= E) return;
    int d = dst[e];
    int pos = atomicAdd(&cursor[d], 1);
    csr[pos] = src[e];
}

// ---------------- gather-mean aggregation ----------------
// One wave per dst node. Half-wave per source row: lanes 0-31 row a (float4 each,
// 16B/lane), lanes 32-63 row b. 4 chains -> 8 edges / 4KB in flight per wave.
__global__ __launch_bounds__(256) void k_agg(const int* __restrict__ rowptr,
                                             const int* __restrict__ csr,
                                             const float* __restrict__ xin,
                                             float* __restrict__ agg, int N) {
    int w = (int)((blockIdx.x * 256u + threadIdx.x) >> 6);
    int lane = threadIdx.x & 63;
    if (w >= N) return;
    int s0 = rowptr[w], s1 = rowptr[w + 1];
    const int half = lane >> 5;
    const int c4 = lane & 31;                 // float4 index within row
    const float4* xin4 = reinterpret_cast<const float4*>(xin);
    float4 a0 = make_float4(0.f, 0.f, 0.f, 0.f);
    float4 a1 = make_float4(0.f, 0.f, 0.f, 0.f);
    float4 a2 = make_float4(0.f, 0.f, 0.f, 0.f);
    float4 a3 = make_float4(0.f, 0.f, 0.f, 0.f);

    for (int p = s0; p < s1; p += 64) {
        int m = s1 - p; if (m > 64) m = 64;
        int my = (p + lane < s1) ? csr[p + lane] : 0;
        int j = 0;
        for (; j + 7 < m; j += 8) {
            int r0 = __shfl(my, j + half);
            int r1 = __shfl(my, j + 2 + half);
            int r2 = __shfl(my, j + 4 + half);
            int r3 = __shfl(my, j + 6 + half);
            float4 v0 = xin4[(size_t)r0 * 32 + c4];
            float4 v1 = xin4[(size_t)r1 * 32 + c4];
            float4 v2 = xin4[(size_t)r2 * 32 + c4];
            float4 v3 = xin4[(size_t)r3 * 32 + c4];
            a0.x += v0.x; a0.y += v0.y; a0.z += v0.z; a0.w += v0.w;
            a1.x += v1.x; a1.y += v1.y; a1.z += v1.z; a1.w += v1.w;
            a2.x += v2.x; a2.y += v2.y; a2.z += v2.z; a2.w += v2.w;
            a3.x += v3.x; a3.y += v3.y; a3.z += v3.z; a3.w += v3.w;
        }
        for (; j + 1 < m; j += 2) {
            int r0 = __shfl(my, j + half);
            float4 v0 = xin4[(size_t)r0 * 32 + c4];
            a0.x += v0.x; a0.y += v0.y; a0.z += v0.z; a0.w += v0.w;
        }
        if (j < m) {
            int r0 = __shfl(my, j);
            float4 v0 = xin4[(size_t)r0 * 32 + c4];
            if (half == 0) {
                a0.x += v0.x; a0.y += v0.y; a0.z += v0.z; a0.w += v0.w;
            }
        }
    }

    float4 s;
    s.x = (a0.x + a1.x) + (a2.x + a3.x);
    s.y = (a0.y + a1.y) + (a2.y + a3.y);
    s.z = (a0.z + a1.z) + (a2.z + a3.z);
    s.w = (a0.w + a1.w) + (a2.w + a3.w);
    s.x += __shfl_xor(s.x, 32);
    s.y += __shfl_xor(s.y, 32);
    s.z += __shfl_xor(s.z, 32);
    s.w += __shfl_xor(s.w, 32);

    float inv = 1.0f / fmaxf((float)(s1 - s0), 1.0f);
    if (half == 0) {
        float4 o = make_float4(s.x * inv, s.y * inv, s.z * inv, s.w * inv);
        nt_store_f4(o, &reinterpret_cast<float4*>(agg)[(size_t)w * 32 + c4]);
    }
}

// ---------------- register-tiled SGEMM (round-1 static schedule) ----------------
// out[i,j] = act( sum_m sum_k A_m[i,k] * W_m[j,k]  + bias[j] )
// Tile: 128 rows x 128 cols per 256-thread block; 8x8 micro-tile per thread.
template <bool RELU, int NMAT, bool NT>
__global__ __launch_bounds__(256) void k_gemm(
    const float* __restrict__ A0, const float* __restrict__ A1,
    const float* __restrict__ W0, const float* __restrict__ W1,
    const float* __restrict__ bias,
    float* __restrict__ out, int N)
{
    __shared__ float sA[128 * 36];   // rows x (BK=32 + pad4)   = 18 KB
    __shared__ float sW[32 * 132];   // k x (128 cols + pad4)   = 16.5 KB

    const int tid = threadIdx.x;
    const int tx  = tid & 15;        // col group: cols tx*4 and 64+tx*4
    const int ty  = tid >> 4;        // row group: rows ty*4 and 64+ty*4
    const int base = blockIdx.x * 128;

    float acc[2][2][4][4];           // [rowhalf][colhalf][ri][ci]
    #pragma unroll
    for (int a = 0; a < 2; ++a)
        #pragma unroll
        for (int b = 0; b < 2; ++b)
            #pragma unroll
            for (int i = 0; i < 4; ++i)
                #pragma unroll
                for (int j = 0; j < 4; ++j)
                    acc[a][b][i][j] = 0.0f;

    const int NCH = NMAT * 4;        // K-chunks of 32
    for (int c_i = 0; c_i < NCH; ++c_i) {
        const float* Asrc = (NMAT == 2 && c_i >= 4) ? A1 : A0;
        const float* Wsrc = (NMAT == 2 && c_i >= 4) ? W1 : W0;
        const int kc = (c_i & 3) * 32;

        __syncthreads();   // previous chunk's reads done before overwrite

        // stage A chunk: 128 rows x 32 k  (1024 float4, 4 per thread)
        #pragma unroll
        for (int it = 0; it < 4; ++it) {
            int idx = it * 256 + tid;
            int row = idx >> 3, kq = idx & 7;
            int grow = base + row;
            if (grow >= N) grow = N - 1;            // clamp; tail rows unused
            float4 v = *reinterpret_cast<const float4*>(
                &Asrc[(size_t)grow * D + kc + kq * 4]);
            *reinterpret_cast<float4*>(&sA[row * 36 + kq * 4]) = v;
        }
        // stage W chunk transposed: sW[k][j] = W[j][kc+k]
        #pragma unroll
        for (int it = 0; it < 4; ++it) {
            int idx = it * 256 + tid;
            int j = idx >> 3, kq = idx & 7;
            float4 v = *reinterpret_cast<const float4*>(&Wsrc[j * D + kc + kq * 4]);
            sW[(kq * 4 + 0) * 132 + j] = v.x;
            sW[(kq * 4 + 1) * 132 + j] = v.y;
            sW[(kq * 4 + 2) * 132 + j] = v.z;
            sW[(kq * 4 + 3) * 132 + j] = v.w;
        }
        __syncthreads();

        // compute: 32 k-steps, unrolled by 4
        #pragma unroll
        for (int kk = 0; kk < 32; kk += 4) {
            float4 av[2][4];   // [rowhalf][ri] : 4 k-values each
            #pragma unroll
            for (int rh = 0; rh < 2; ++rh)
                #pragma unroll
                for (int ri = 0; ri < 4; ++ri)
                    av[rh][ri] = *reinterpret_cast<const float4*>(
                        &sA[(rh * 64 + ty * 4 + ri) * 36 + kk]);
            float4 wv[4][2];   // [kq][colhalf] : 4 cols each
            #pragma unroll
            for (int kq = 0; kq < 4; ++kq)
                #pragma unroll
                for (int c = 0; c < 2; ++c)
                    wv[kq][c] = *reinterpret_cast<const float4*>(
                        &sW[(kk + kq) * 132 + c * 64 + tx * 4]);
            #pragma unroll
            for (int kq = 0; kq < 4; ++kq) {
                #pragma unroll
                for (int rh = 0; rh < 2; ++rh) {
                    #pragma unroll
                    for (int ri = 0; ri < 4; ++ri) {
                        float a = reinterpret_cast<const float*>(&av[rh][ri])[kq];
                        #pragma unroll
                        for (int c = 0; c < 2; ++c) {
                            float4 w = wv[kq][c];
                            acc[rh][c][ri][0] = fmaf(a, w.x, acc[rh][c][ri][0]);
                            acc[rh][c][ri][1] = fmaf(a, w.y, acc[rh][c][ri][1]);
                            acc[rh][c][ri][2] = fmaf(a, w.z, acc[rh][c][ri][2]);
                            acc[rh][c][ri][3] = fmaf(a, w.w, acc[rh][c][ri][3]);
                        }
                    }
                }
            }
        }
    }

    // epilogue: bias + activation + store
    float4 b4[2];
    b4[0] = *reinterpret_cast<const float4*>(&bias[tx * 4]);
    b4[1] = *reinterpret_cast<const float4*>(&bias[64 + tx * 4]);
    #pragma unroll
    for (int rh = 0; rh < 2; ++rh) {
        #pragma unroll
        for (int ri = 0; ri < 4; ++ri) {
            int row = base + rh * 64 + ty * 4 + ri;
            if (row < N) {
                #pragma unroll
                for (int c = 0; c < 2; ++c) {
                    float4 o;
                    o.x = acc[rh][c][ri][0] + b4[c].x;
                    o.y = acc[rh][c][ri][1] + b4[c].y;
                    o.z = acc[rh][c][ri][2] + b4[c].z;
                    o.w = acc[rh][c][ri][3] + b4[c].w;
                    if (RELU) {
                        o.x = fmaxf(o.x, 0.0f); o.y = fmaxf(o.y, 0.0f);
                        o.z = fmaxf(o.z, 0.0f); o.w = fmaxf(o.w, 0.0f);
                    }
                    float4* dst = reinterpret_cast<float4*>(
                        &out[(size_t)row * D + c * 64 + tx * 4]);
                    if (NT) nt_store_f4(o, dst);
                    else    *dst = o;
                }
            }
        }
    }
}

extern "C" void kernel_launch(void* const* d_in, const int* in_sizes, int n_in,
                              void* d_out, int out_size, void* d_ws, size_t ws_size,
                              hipStream_t stream) {
    const float* x   = (const float*)d_in[0];
    const int*   ei  = (const int*)d_in[1];
    const float* Wl0 = (const float*)d_in[2];
    const float* bl0 = (const float*)d_in[3];
    const float* Wr0 = (const float*)d_in[4];
    const float* Wl1 = (const float*)d_in[5];
    const float* bl1 = (const float*)d_in[6];
    const float* Wr1 = (const float*)d_in[7];
    const float* Wv  = (const float*)d_in[8];
    const float* bv  = (const float*)d_in[9];
    const float* Wt  = (const float*)d_in[10];
    const float* bt  = (const float*)d_in[11];

    const int N = in_sizes[0] / D;       // 100000
    const int E = in_sizes[1] / 2;       // 1600000
    const int* srcv = ei;
    const int* dstv = ei + E;

    float* out  = (float*)d_out;
    float* h    = out;                        // [0, N*D)      final output 0
    float* h1   = out + (size_t)N * D;        // scratch, later x_vision
    float* aggb = out + 2 * (size_t)N * D;    // scratch, later x_text

    // CSR workspace: deg(N) | rowptr(N+1) | cursor(N) | csr(E)  — ints
    size_t need = ((size_t)(3 * N + 1) + (size_t)E) * sizeof(int);
    int* wsI = (ws_size >= need) ? (int*)d_ws
                                 : (int*)h;   // fallback: h region is free until layer-1 gemm
    int* degI   = wsI;
    int* rowptr = wsI + N;
    int* cursor = wsI + 2 * N + 1;
    int* csr    = wsI + 2 * N + 1 + N;

    (void)hipMemsetAsync(degI, 0, (size_t)N * sizeof(int), stream);
    k_deg <<<(E + 255) / 256, 256, 0, stream>>>(dstv, degI, E);
    k_scan<<<1, 1024, 0, stream>>>(degI, rowptr, N);
    (void)hipMemcpyAsync(cursor, rowptr, (size_t)N * sizeof(int),
                         hipMemcpyDeviceToDevice, stream);
    k_fill<<<(E + 255) / 256, 256, 0, stream>>>(srcv, dstv, cursor, csr, E);

    const int agg_blocks  = (int)(((size_t)N * 64 + 255) / 256);
    const int gemm_blocks = (N + 127) / 128;

    // ---- layer 0 ----
    k_agg<<<agg_blocks, 256, 0, stream>>>(rowptr, csr, x, aggb, N);
    k_gemm<true, 2, false><<<gemm_blocks, 256, 0, stream>>>(aggb, x, Wl0, Wr0, bl0, h1, N);

    // ---- layer 1 ----
    k_agg<<<agg_blocks, 256, 0, stream>>>(rowptr, csr, h1, aggb, N);
    k_gemm<false, 2, false><<<gemm_blocks, 256, 0, stream>>>(aggb, h1, Wl1, Wr1, bl1, h, N);

    // ---- heads: xv = relu(h@Wv^T+bv), xt = relu(h@Wt^T+bt) ----
    k_gemm<true, 1, true><<<gemm_blocks, 256, 0, stream>>>(h, nullptr, Wv, nullptr, bv,
                                                           out + (size_t)N * D, N);
    k_gemm<true, 1, true><<<gemm_blocks, 256, 0, stream>>>(h, nullptr, Wt, nullptr, bt,
                                                           out + 2 * (size_t)N * D, N);
}

// Round 5
// 738.974 us; speedup vs baseline: 2.4717x; 1.0997x over previous
//
#include <hip/hip_runtime.h>

#define D 128

typedef float nfloat4 __attribute__((ext_vector_type(4)));

__device__ __forceinline__ void nt_store_f4(const float4& v, float4* p) {
    nfloat4 nv;
    nv.x = v.x; nv.y = v.y; nv.z = v.z; nv.w = v.w;
    __builtin_nontemporal_store(nv, reinterpret_cast<nfloat4*>(p));
}

// ---------------- int degree histogram ----------------
__global__ void k_deg(const int* __restrict__ dst, int* __restrict__ deg, int E) {
    int e = blockIdx.x * blockDim.x + threadIdx.x;
    if (e < E) atomicAdd(&deg[dst[e]], 1);
}

// ---------------- multi-block exclusive scan, phase A ----------------
// 25 blocks x 1024 threads x 4 elems. Block-local exclusive scan -> rowptr,
// block total -> bsum[b].
__global__ __launch_bounds__(1024) void k_scan_a(const int* __restrict__ deg,
                                                 int* __restrict__ rowptr,
                                                 int* __restrict__ bsum, int N) {
    __shared__ int wsum[16];
    __shared__ int wscan[16];
    const int tid = threadIdx.x, lane = tid & 63, wid = tid >> 6;
    const int i = blockIdx.x * 4096 + tid * 4;
    // int4 load is safe: deg is followed by rowptr/cursor/csr storage
    int4 v = *reinterpret_cast<const int4*>(&deg[i]);
    int v0 = (i     < N) ? v.x : 0;
    int v1 = (i + 1 < N) ? v.y : 0;
    int v2 = (i + 2 < N) ? v.z : 0;
    int v3 = (i + 3 < N) ? v.w : 0;
    const int t = v0 + v1 + v2 + v3;
    int x = t;
    #pragma unroll
    for (int off = 1; off < 64; off <<= 1) {
        int u = __shfl_up(x, off);
        if (lane >= off) x += u;
    }
    if (lane == 63) wsum[wid] = x;
    __syncthreads();
    if (wid == 0) {
        int s = (lane < 16) ? wsum[lane] : 0;
        #pragma unroll
        for (int off = 1; off < 16; off <<= 1) {
            int u = __shfl_up(s, off);
            if (lane >= off) s += u;
        }
        if (lane < 16) wscan[lane] = s;
    }
    __syncthreads();
    int excl = x - t + ((wid > 0) ? wscan[wid - 1] : 0);
    if (i     < N) rowptr[i]     = excl;
    if (i + 1 < N) rowptr[i + 1] = excl + v0;
    if (i + 2 < N) rowptr[i + 2] = excl + v0 + v1;
    if (i + 3 < N) rowptr[i + 3] = excl + v0 + v1 + v2;
    if (tid == 0) bsum[blockIdx.x] = wscan[15];
}

// ---------------- scan phase B: add block offsets, seed cursor ----------------
__global__ __launch_bounds__(1024) void k_scan_b(int* __restrict__ rowptr,
                                                 int* __restrict__ cursor,
                                                 const int* __restrict__ bsum,
                                                 int N, int nb) {
    __shared__ int s_off;
    if (threadIdx.x == 0) {
        int o = 0;
        for (int b = 0; b < (int)blockIdx.x; ++b) o += bsum[b];
        s_off = o;
        if ((int)blockIdx.x == nb - 1) rowptr[N] = o + bsum[nb - 1];
    }
    __syncthreads();
    const int off = s_off;
    const int i = blockIdx.x * 4096 + threadIdx.x * 4;
    if (i + 3 < N) {
        int4 r = *reinterpret_cast<const int4*>(&rowptr[i]);
        r.x += off; r.y += off; r.z += off; r.w += off;
        *reinterpret_cast<int4*>(&rowptr[i]) = r;
        *reinterpret_cast<int4*>(&cursor[i]) = r;
    } else {
        #pragma unroll
        for (int k = 0; k < 4; ++k) {
            int ii = i + k;
            if (ii < N) {
                int r = rowptr[ii] + off;
                rowptr[ii] = r;
                cursor[ii] = r;
            }
        }
    }
}

// ---------------- CSR fill: 4 edges/thread, nontemporal scatter ----------------
__global__ void k_fill(const int* __restrict__ src, const int* __restrict__ dst,
                       int* __restrict__ cursor, int* __restrict__ csr, int E) {
    int e0 = (blockIdx.x * blockDim.x + threadIdx.x) * 4;
    if (e0 >= E) return;
    if (e0 + 3 < E) {
        int4 d4 = *reinterpret_cast<const int4*>(&dst[e0]);
        int4 s4 = *reinterpret_cast<const int4*>(&src[e0]);
        int p0 = atomicAdd(&cursor[d4.x], 1);
        int p1 = atomicAdd(&cursor[d4.y], 1);
        int p2 = atomicAdd(&cursor[d4.z], 1);
        int p3 = atomicAdd(&cursor[d4.w], 1);
        __builtin_nontemporal_store(s4.x, &csr[p0]);
        __builtin_nontemporal_store(s4.y, &csr[p1]);
        __builtin_nontemporal_store(s4.z, &csr[p2]);
        __builtin_nontemporal_store(s4.w, &csr[p3]);
    } else {
        for (int e = e0; e < E; ++e) {
            int p = atomicAdd(&cursor[dst[e]], 1);
            __builtin_nontemporal_store(src[e], &csr[p]);
        }
    }
}

// ---------------- gather-mean aggregation ----------------
// One wave per dst node. Half-wave per source row: lanes 0-31 row a (float4 each,
// 16B/lane), lanes 32-63 row b. 4 chains -> 8 edges / 4KB in flight per wave.
__global__ __launch_bounds__(256) void k_agg(const int* __restrict__ rowptr,
                                             const int* __restrict__ csr,
                                             const float* __restrict__ xin,
                                             float* __restrict__ agg, int N) {
    int w = (int)((blockIdx.x * 256u + threadIdx.x) >> 6);
    int lane = threadIdx.x & 63;
    if (w >= N) return;
    int s0 = rowptr[w], s1 = rowptr[w + 1];
    const int half = lane >> 5;
    const int c4 = lane & 31;                 // float4 index within row
    const float4* xin4 = reinterpret_cast<const float4*>(xin);
    float4 a0 = make_float4(0.f, 0.f, 0.f, 0.f);
    float4 a1 = make_float4(0.f, 0.f, 0.f, 0.f);
    float4 a2 = make_float4(0.f, 0.f, 0.f, 0.f);
    float4 a3 = make_float4(0.f, 0.f, 0.f, 0.f);

    for (int p = s0; p < s1; p += 64) {
        int m = s1 - p; if (m > 64) m = 64;
        int my = (p + lane < s1) ? csr[p + lane] : 0;
        int j = 0;
        for (; j + 7 < m; j += 8) {
            int r0 = __shfl(my, j + half);
            int r1 = __shfl(my, j + 2 + half);
            int r2 = __shfl(my, j + 4 + half);
            int r3 = __shfl(my, j + 6 + half);
            float4 v0 = xin4[(size_t)r0 * 32 + c4];
            float4 v1 = xin4[(size_t)r1 * 32 + c4];
            float4 v2 = xin4[(size_t)r2 * 32 + c4];
            float4 v3 = xin4[(size_t)r3 * 32 + c4];
            a0.x += v0.x; a0.y += v0.y; a0.z += v0.z; a0.w += v0.w;
            a1.x += v1.x; a1.y += v1.y; a1.z += v1.z; a1.w += v1.w;
            a2.x += v2.x; a2.y += v2.y; a2.z += v2.z; a2.w += v2.w;
            a3.x += v3.x; a3.y += v3.y; a3.z += v3.z; a3.w += v3.w;
        }
        for (; j + 1 < m; j += 2) {
            int r0 = __shfl(my, j + half);
            float4 v0 = xin4[(size_t)r0 * 32 + c4];
            a0.x += v0.x; a0.y += v0.y; a0.z += v0.z; a0.w += v0.w;
        }
        if (j < m) {
            int r0 = __shfl(my, j);
            float4 v0 = xin4[(size_t)r0 * 32 + c4];
            if (half == 0) {
                a0.x += v0.x; a0.y += v0.y; a0.z += v0.z; a0.w += v0.w;
            }
        }
    }

    float4 s;
    s.x = (a0.x + a1.x) + (a2.x + a3.x);
    s.y = (a0.y + a1.y) + (a2.y + a3.y);
    s.z = (a0.z + a1.z) + (a2.z + a3.z);
    s.w = (a0.w + a1.w) + (a2.w + a3.w);
    s.x += __shfl_xor(s.x, 32);
    s.y += __shfl_xor(s.y, 32);
    s.z += __shfl_xor(s.z, 32);
    s.w += __shfl_xor(s.w, 32);

    float inv = 1.0f / fmaxf((float)(s1 - s0), 1.0f);
    if (half == 0) {
        float4 o = make_float4(s.x * inv, s.y * inv, s.z * inv, s.w * inv);
        nt_store_f4(o, &reinterpret_cast<float4*>(agg)[(size_t)w * 32 + c4]);
    }
}

// ---------------- register-tiled SGEMM (static schedule) ----------------
// out[i,j] = act( sum_m sum_k A_m[i,k] * W_m[j,k]  + bias[j] )
// Tile: 128 rows x 128 cols per 256-thread block; 8x8 micro-tile per thread.
template <bool RELU, int NMAT, bool NT>
__global__ __launch_bounds__(256) void k_gemm(
    const float* __restrict__ A0, const float* __restrict__ A1,
    const float* __restrict__ W0, const float* __restrict__ W1,
    const float* __restrict__ bias,
    float* __restrict__ out, int N)
{
    __shared__ float sA[128 * 36];   // rows x (BK=32 + pad4)   = 18 KB
    __shared__ float sW[32 * 132];   // k x (128 cols + pad4)   = 16.5 KB

    const int tid = threadIdx.x;
    const int tx  = tid & 15;        // col group: cols tx*4 and 64+tx*4
    const int ty  = tid >> 4;        // row group: rows ty*4 and 64+ty*4
    const int base = blockIdx.x * 128;

    float acc[2][2][4][4];           // [rowhalf][colhalf][ri][ci]
    #pragma unroll
    for (int a = 0; a < 2; ++a)
        #pragma unroll
        for (int b = 0; b < 2; ++b)
            #pragma unroll
            for (int i = 0; i < 4; ++i)
                #pragma unroll
                for (int j = 0; j < 4; ++j)
                    acc[a][b][i][j] = 0.0f;

    const int NCH = NMAT * 4;        // K-chunks of 32
    for (int c_i = 0; c_i < NCH; ++c_i) {
        const float* Asrc = (NMAT == 2 && c_i >= 4) ? A1 : A0;
        const float* Wsrc = (NMAT == 2 && c_i >= 4) ? W1 : W0;
        const int kc = (c_i & 3) * 32;

        __syncthreads();   // previous chunk's reads done before overwrite

        // stage A chunk: 128 rows x 32 k  (1024 float4, 4 per thread)
        #pragma unroll
        for (int it = 0; it < 4; ++it) {
            int idx = it * 256 + tid;
            int row = idx >> 3, kq = idx & 7;
            int grow = base + row;
            if (grow >= N) grow = N - 1;            // clamp; tail rows unused
            float4 v = *reinterpret_cast<const float4*>(
                &Asrc[(size_t)grow * D + kc + kq * 4]);
            *reinterpret_cast<float4*>(&sA[row * 36 + kq * 4]) = v;
        }
        // stage W chunk transposed: sW[k][j] = W[j][kc+k]
        #pragma unroll
        for (int it = 0; it < 4; ++it) {
            int idx = it * 256 + tid;
            int j = idx >> 3, kq = idx & 7;
            float4 v = *reinterpret_cast<const float4*>(&Wsrc[j * D + kc + kq * 4]);
            sW[(kq * 4 + 0) * 132 + j] = v.x;
            sW[(kq * 4 + 1) * 132 + j] = v.y;
            sW[(kq * 4 + 2) * 132 + j] = v.z;
            sW[(kq * 4 + 3) * 132 + j] = v.w;
        }
        __syncthreads();

        // compute: 32 k-steps, unrolled by 4
        #pragma unroll
        for (int kk = 0; kk < 32; kk += 4) {
            float4 av[2][4];   // [rowhalf][ri] : 4 k-values each
            #pragma unroll
            for (int rh = 0; rh < 2; ++rh)
                #pragma unroll
                for (int ri = 0; ri < 4; ++ri)
                    av[rh][ri] = *reinterpret_cast<const float4*>(
                        &sA[(rh * 64 + ty * 4 + ri) * 36 + kk]);
            float4 wv[4][2];   // [kq][colhalf] : 4 cols each
            #pragma unroll
            for (int kq = 0; kq < 4; ++kq)
                #pragma unroll
                for (int c = 0; c < 2; ++c)
                    wv[kq][c] = *reinterpret_cast<const float4*>(
                        &sW[(kk + kq) * 132 + c * 64 + tx * 4]);
            #pragma unroll
            for (int kq = 0; kq < 4; ++kq) {
                #pragma unroll
                for (int rh = 0; rh < 2; ++rh) {
                    #pragma unroll
                    for (int ri = 0; ri < 4; ++ri) {
                        float a = reinterpret_cast<const float*>(&av[rh][ri])[kq];
                        #pragma unroll
                        for (int c = 0; c < 2; ++c) {
                            float4 w = wv[kq][c];
                            acc[rh][c][ri][0] = fmaf(a, w.x, acc[rh][c][ri][0]);
                            acc[rh][c][ri][1] = fmaf(a, w.y, acc[rh][c][ri][1]);
                            acc[rh][c][ri][2] = fmaf(a, w.z, acc[rh][c][ri][2]);
                            acc[rh][c][ri][3] = fmaf(a, w.w, acc[rh][c][ri][3]);
                        }
                    }
                }
            }
        }
    }

    // epilogue: bias + activation + store
    float4 b4[2];
    b4[0] = *reinterpret_cast<const float4*>(&bias[tx * 4]);
    b4[1] = *reinterpret_cast<const float4*>(&bias[64 + tx * 4]);
    #pragma unroll
    for (int rh = 0; rh < 2; ++rh) {
        #pragma unroll
        for (int ri = 0; ri < 4; ++ri) {
            int row = base + rh * 64 + ty * 4 + ri;
            if (row < N) {
                #pragma unroll
                for (int c = 0; c < 2; ++c) {
                    float4 o;
                    o.x = acc[rh][c][ri][0] + b4[c].x;
                    o.y = acc[rh][c][ri][1] + b4[c].y;
                    o.z = acc[rh][c][ri][2] + b4[c].z;
                    o.w = acc[rh][c][ri][3] + b4[c].w;
                    if (RELU) {
                        o.x = fmaxf(o.x, 0.0f); o.y = fmaxf(o.y, 0.0f);
                        o.z = fmaxf(o.z, 0.0f); o.w = fmaxf(o.w, 0.0f);
                    }
                    float4* dst = reinterpret_cast<float4*>(
                        &out[(size_t)row * D + c * 64 + tx * 4]);
                    if (NT) nt_store_f4(o, dst);
                    else    *dst = o;
                }
            }
        }
    }
}

extern "C" void kernel_launch(void* const* d_in, const int* in_sizes, int n_in,
                              void* d_out, int out_size, void* d_ws, size_t ws_size,
                              hipStream_t stream) {
    const float* x   = (const float*)d_in[0];
    const int*   ei  = (const int*)d_in[1];
    const float* Wl0 = (const float*)d_in[2];
    const float* bl0 = (const float*)d_in[3];
    const float* Wr0 = (const float*)d_in[4];
    const float* Wl1 = (const float*)d_in[5];
    const float* bl1 = (const float*)d_in[6];
    const float* Wr1 = (const float*)d_in[7];
    const float* Wv  = (const float*)d_in[8];
    const float* bv  = (const float*)d_in[9];
    const float* Wt  = (const float*)d_in[10];
    const float* bt  = (const float*)d_in[11];

    const int N = in_sizes[0] / D;       // 100000
    const int E = in_sizes[1] / 2;       // 1600000
    const int* srcv = ei;
    const int* dstv = ei + E;

    float* out  = (float*)d_out;
    float* h    = out;                        // [0, N*D)      final output 0
    float* h1   = out + (size_t)N * D;        // scratch, later x_vision
    float* aggb = out + 2 * (size_t)N * D;    // scratch, later x_text

    const int nb = (N + 4095) / 4096;

    // CSR workspace: deg(N) | rowptr(N+1) | cursor(N) | csr(E) | bsum(nb) — ints
    size_t need = ((size_t)(3 * N + 1) + (size_t)E + (size_t)nb) * sizeof(int);
    int* wsI = (ws_size >= need) ? (int*)d_ws
                                 : (int*)h;   // fallback: h region is free until layer-1 gemm
    int* degI   = wsI;
    int* rowptr = wsI + N;
    int* cursor = wsI + 2 * N + 1;
    int* csr    = wsI + 3 * N + 1;
    int* bsum   = wsI + 3 * N + 1 + E;

    (void)hipMemsetAsync(degI, 0, (size_t)N * sizeof(int), stream);
    k_deg <<<(E + 255) / 256, 256, 0, stream>>>(dstv, degI, E);
    k_scan_a<<<nb, 1024, 0, stream>>>(degI, rowptr, bsum, N);
    k_scan_b<<<nb, 1024, 0, stream>>>(rowptr, cursor, bsum, N, nb);
    k_fill<<<(E + 1023) / 1024, 256, 0, stream>>>(srcv, dstv, cursor, csr, E);

    const int agg_blocks  = (int)(((size_t)N * 64 + 255) / 256);
    const int gemm_blocks = (N + 127) / 128;

    // ---- layer 0 ----
    k_agg<<<agg_blocks, 256, 0, stream>>>(rowptr, csr, x, aggb, N);
    k_gemm<true, 2, false><<<gemm_blocks, 256, 0, stream>>>(aggb, x, Wl0, Wr0, bl0, h1, N);

    // ---- layer 1 ----
    k_agg<<<agg_blocks, 256, 0, stream>>>(rowptr, csr, h1, aggb, N);
    k_gemm<false, 2, false><<<gemm_blocks, 256, 0, stream>>>(aggb, h1, Wl1, Wr1, bl1, h, N);

    // ---- heads: xv = relu(h@Wv^T+bv), xt = relu(h@Wt^T+bt) ----
    k_gemm<true, 1, true><<<gemm_blocks, 256, 0, stream>>>(h, nullptr, Wv, nullptr, bv,
                                                           out + (size_t)N * D, N);
    k_gemm<true, 1, true><<<gemm_blocks, 256, 0, stream>>>(h, nullptr, Wt, nullptr, bt,
                                                           out + 2 * (size_t)N * D, N);
}

// Round 6
// 691.245 us; speedup vs baseline: 2.6424x; 1.0690x over previous
//
#include <hip/hip_runtime.h>

#define D 128
#define SEG_SHIFT 14              // 16384-node atomic/scatter window (~0.9MB csr/pass)

typedef float nfloat4 __attribute__((ext_vector_type(4)));

__device__ __forceinline__ void nt_store_f4(const float4& v, float4* p) {
    nfloat4 nv;
    nv.x = v.x; nv.y = v.y; nv.z = v.z; nv.w = v.w;
    __builtin_nontemporal_store(nv, reinterpret_cast<nfloat4*>(p));
}

// ---------------- segmented degree histogram ----------------
// Pass p touches only dst in [p<<SEG_SHIFT, (p+1)<<SEG_SHIFT): atomics confined
// to a 64KB L2-resident window -> line writebacks merge instead of thrashing.
__global__ __launch_bounds__(256) void k_deg(const int* __restrict__ dst,
                                             int* __restrict__ deg, int E, int nseg) {
    const int stride = gridDim.x * blockDim.x;
    const int t0 = blockIdx.x * blockDim.x + threadIdx.x;
    for (int seg = 0; seg < nseg; ++seg) {
        const int lo = seg << SEG_SHIFT, hi = lo + (1 << SEG_SHIFT);
        for (int e = t0; e < E; e += stride) {
            int d = dst[e];
            if (d >= lo && d < hi) atomicAdd(&deg[d], 1);
        }
    }
}

// ---------------- multi-block exclusive scan, phase A ----------------
__global__ __launch_bounds__(1024) void k_scan_a(const int* __restrict__ deg,
                                                 int* __restrict__ rowptr,
                                                 int* __restrict__ bsum, int N) {
    __shared__ int wsum[16];
    __shared__ int wscan[16];
    const int tid = threadIdx.x, lane = tid & 63, wid = tid >> 6;
    const int i = blockIdx.x * 4096 + tid * 4;
    // int4 load is safe: deg is followed by rowptr/cursor/csr storage
    int4 v = *reinterpret_cast<const int4*>(&deg[i]);
    int v0 = (i     < N) ? v.x : 0;
    int v1 = (i + 1 < N) ? v.y : 0;
    int v2 = (i + 2 < N) ? v.z : 0;
    int v3 = (i + 3 < N) ? v.w : 0;
    const int t = v0 + v1 + v2 + v3;
    int x = t;
    #pragma unroll
    for (int off = 1; off < 64; off <<= 1) {
        int u = __shfl_up(x, off);
        if (lane >= off) x += u;
    }
    if (lane == 63) wsum[wid] = x;
    __syncthreads();
    if (wid == 0) {
        int s = (lane < 16) ? wsum[lane] : 0;
        #pragma unroll
        for (int off = 1; off < 16; off <<= 1) {
            int u = __shfl_up(s, off);
            if (lane >= off) s += u;
        }
        if (lane < 16) wscan[lane] = s;
    }
    __syncthreads();
    int excl = x - t + ((wid > 0) ? wscan[wid - 1] : 0);
    if (i     < N) rowptr[i]     = excl;
    if (i + 1 < N) rowptr[i + 1] = excl + v0;
    if (i + 2 < N) rowptr[i + 2] = excl + v0 + v1;
    if (i + 3 < N) rowptr[i + 3] = excl + v0 + v1 + v2;
    if (tid == 0) bsum[blockIdx.x] = wscan[15];
}

// ---------------- scan phase B: add block offsets, seed cursor ----------------
__global__ __launch_bounds__(1024) void k_scan_b(int* __restrict__ rowptr,
                                                 int* __restrict__ cursor,
                                                 const int* __restrict__ bsum,
                                                 int N, int nb) {
    __shared__ int s_off;
    if (threadIdx.x == 0) {
        int o = 0;
        for (int b = 0; b < (int)blockIdx.x; ++b) o += bsum[b];
        s_off = o;
        if ((int)blockIdx.x == nb - 1) rowptr[N] = o + bsum[nb - 1];
    }
    __syncthreads();
    const int off = s_off;
    const int i = blockIdx.x * 4096 + threadIdx.x * 4;
    if (i + 3 < N) {
        int4 r = *reinterpret_cast<const int4*>(&rowptr[i]);
        r.x += off; r.y += off; r.z += off; r.w += off;
        *reinterpret_cast<int4*>(&rowptr[i]) = r;
        *reinterpret_cast<int4*>(&cursor[i]) = r;
    } else {
        #pragma unroll
        for (int k = 0; k < 4; ++k) {
            int ii = i + k;
            if (ii < N) {
                int r = rowptr[ii] + off;
                rowptr[ii] = r;
                cursor[ii] = r;
            }
        }
    }
}

// ---------------- segmented CSR fill ----------------
// Same windowing as k_deg: csr scatter confined to ~0.9MB/pass so partial-line
// writes merge in L2 instead of 16x write amplification.
__global__ __launch_bounds__(256) void k_fill(const int* __restrict__ src,
                                              const int* __restrict__ dst,
                                              int* __restrict__ cursor,
                                              int* __restrict__ csr, int E, int nseg) {
    const int stride = gridDim.x * blockDim.x;
    const int t0 = blockIdx.x * blockDim.x + threadIdx.x;
    for (int seg = 0; seg < nseg; ++seg) {
        const int lo = seg << SEG_SHIFT, hi = lo + (1 << SEG_SHIFT);
        for (int e = t0; e < E; e += stride) {
            int d = dst[e];
            if (d >= lo && d < hi) {
                int p = atomicAdd(&cursor[d], 1);
                csr[p] = src[e];
            }
        }
    }
}

// ---------------- gather-mean aggregation ----------------
// One wave per dst node. Half-wave per source row: lanes 0-31 row a (float4 each,
// 16B/lane), lanes 32-63 row b. 4 chains -> 8 edges / 4KB in flight per wave.
__global__ __launch_bounds__(256) void k_agg(const int* __restrict__ rowptr,
                                             const int* __restrict__ csr,
                                             const float* __restrict__ xin,
                                             float* __restrict__ agg, int N) {
    int w = (int)((blockIdx.x * 256u + threadIdx.x) >> 6);
    int lane = threadIdx.x & 63;
    if (w >= N) return;
    int s0 = rowptr[w], s1 = rowptr[w + 1];
    const int half = lane >> 5;
    const int c4 = lane & 31;                 // float4 index within row
    const float4* xin4 = reinterpret_cast<const float4*>(xin);
    float4 a0 = make_float4(0.f, 0.f, 0.f, 0.f);
    float4 a1 = make_float4(0.f, 0.f, 0.f, 0.f);
    float4 a2 = make_float4(0.f, 0.f, 0.f, 0.f);
    float4 a3 = make_float4(0.f, 0.f, 0.f, 0.f);

    for (int p = s0; p < s1; p += 64) {
        int m = s1 - p; if (m > 64) m = 64;
        int my = (p + lane < s1) ? csr[p + lane] : 0;
        int j = 0;
        for (; j + 7 < m; j += 8) {
            int r0 = __shfl(my, j + half);
            int r1 = __shfl(my, j + 2 + half);
            int r2 = __shfl(my, j + 4 + half);
            int r3 = __shfl(my, j + 6 + half);
            float4 v0 = xin4[(size_t)r0 * 32 + c4];
            float4 v1 = xin4[(size_t)r1 * 32 + c4];
            float4 v2 = xin4[(size_t)r2 * 32 + c4];
            float4 v3 = xin4[(size_t)r3 * 32 + c4];
            a0.x += v0.x; a0.y += v0.y; a0.z += v0.z; a0.w += v0.w;
            a1.x += v1.x; a1.y += v1.y; a1.z += v1.z; a1.w += v1.w;
            a2.x += v2.x; a2.y += v2.y; a2.z += v2.z; a2.w += v2.w;
            a3.x += v3.x; a3.y += v3.y; a3.z += v3.z; a3.w += v3.w;
        }
        for (; j + 1 < m; j += 2) {
            int r0 = __shfl(my, j + half);
            float4 v0 = xin4[(size_t)r0 * 32 + c4];
            a0.x += v0.x; a0.y += v0.y; a0.z += v0.z; a0.w += v0.w;
        }
        if (j < m) {
            int r0 = __shfl(my, j);
            float4 v0 = xin4[(size_t)r0 * 32 + c4];
            if (half == 0) {
                a0.x += v0.x; a0.y += v0.y; a0.z += v0.z; a0.w += v0.w;
            }
        }
    }

    float4 s;
    s.x = (a0.x + a1.x) + (a2.x + a3.x);
    s.y = (a0.y + a1.y) + (a2.y + a3.y);
    s.z = (a0.z + a1.z) + (a2.z + a3.z);
    s.w = (a0.w + a1.w) + (a2.w + a3.w);
    s.x += __shfl_xor(s.x, 32);
    s.y += __shfl_xor(s.y, 32);
    s.z += __shfl_xor(s.z, 32);
    s.w += __shfl_xor(s.w, 32);

    float inv = 1.0f / fmaxf((float)(s1 - s0), 1.0f);
    if (half == 0) {
        float4 o = make_float4(s.x * inv, s.y * inv, s.z * inv, s.w * inv);
        nt_store_f4(o, &reinterpret_cast<float4*>(agg)[(size_t)w * 32 + c4]);
    }
}

// ---------------- register-tiled SGEMM (static schedule) ----------------
// out[i,j] = act( sum_m sum_k A_m[i,k] * W_m[j,k]  + bias[j] )
// Tile: 128 rows x 128 cols per 256-thread block; 8x8 micro-tile per thread.
template <bool RELU, int NMAT, bool NT>
__global__ __launch_bounds__(256) void k_gemm(
    const float* __restrict__ A0, const float* __restrict__ A1,
    const float* __restrict__ W0, const float* __restrict__ W1,
    const float* __restrict__ bias,
    float* __restrict__ out, int N)
{
    __shared__ float sA[128 * 36];   // rows x (BK=32 + pad4)   = 18 KB
    __shared__ float sW[32 * 132];   // k x (128 cols + pad4)   = 16.5 KB

    const int tid = threadIdx.x;
    const int tx  = tid & 15;        // col group: cols tx*4 and 64+tx*4
    const int ty  = tid >> 4;        // row group: rows ty*4 and 64+ty*4
    const int base = blockIdx.x * 128;

    float acc[2][2][4][4];           // [rowhalf][colhalf][ri][ci]
    #pragma unroll
    for (int a = 0; a < 2; ++a)
        #pragma unroll
        for (int b = 0; b < 2; ++b)
            #pragma unroll
            for (int i = 0; i < 4; ++i)
                #pragma unroll
                for (int j = 0; j < 4; ++j)
                    acc[a][b][i][j] = 0.0f;

    const int NCH = NMAT * 4;        // K-chunks of 32
    for (int c_i = 0; c_i < NCH; ++c_i) {
        const float* Asrc = (NMAT == 2 && c_i >= 4) ? A1 : A0;
        const float* Wsrc = (NMAT == 2 && c_i >= 4) ? W1 : W0;
        const int kc = (c_i & 3) * 32;

        __syncthreads();   // previous chunk's reads done before overwrite

        // stage A chunk: 128 rows x 32 k  (1024 float4, 4 per thread)
        #pragma unroll
        for (int it = 0; it < 4; ++it) {
            int idx = it * 256 + tid;
            int row = idx >> 3, kq = idx & 7;
            int grow = base + row;
            if (grow >= N) grow = N - 1;            // clamp; tail rows unused
            float4 v = *reinterpret_cast<const float4*>(
                &Asrc[(size_t)grow * D + kc + kq * 4]);
            *reinterpret_cast<float4*>(&sA[row * 36 + kq * 4]) = v;
        }
        // stage W chunk transposed: sW[k][j] = W[j][kc+k]
        #pragma unroll
        for (int it = 0; it < 4; ++it) {
            int idx = it * 256 + tid;
            int j = idx >> 3, kq = idx & 7;
            float4 v = *reinterpret_cast<const float4*>(&Wsrc[j * D + kc + kq * 4]);
            sW[(kq * 4 + 0) * 132 + j] = v.x;
            sW[(kq * 4 + 1) * 132 + j] = v.y;
            sW[(kq * 4 + 2) * 132 + j] = v.z;
            sW[(kq * 4 + 3) * 132 + j] = v.w;
        }
        __syncthreads();

        // compute: 32 k-steps, unrolled by 4
        #pragma unroll
        for (int kk = 0; kk < 32; kk += 4) {
            float4 av[2][4];   // [rowhalf][ri] : 4 k-values each
            #pragma unroll
            for (int rh = 0; rh < 2; ++rh)
                #pragma unroll
                for (int ri = 0; ri < 4; ++ri)
                    av[rh][ri] = *reinterpret_cast<const float4*>(
                        &sA[(rh * 64 + ty * 4 + ri) * 36 + kk]);
            float4 wv[4][2];   // [kq][colhalf] : 4 cols each
            #pragma unroll
            for (int kq = 0; kq < 4; ++kq)
                #pragma unroll
                for (int c = 0; c < 2; ++c)
                    wv[kq][c] = *reinterpret_cast<const float4*>(
                        &sW[(kk + kq) * 132 + c * 64 + tx * 4]);
            #pragma unroll
            for (int kq = 0; kq < 4; ++kq) {
                #pragma unroll
                for (int rh = 0; rh < 2; ++rh) {
                    #pragma unroll
                    for (int ri = 0; ri < 4; ++ri) {
                        float a = reinterpret_cast<const float*>(&av[rh][ri])[kq];
                        #pragma unroll
                        for (int c = 0; c < 2; ++c) {
                            float4 w = wv[kq][c];
                            acc[rh][c][ri][0] = fmaf(a, w.x, acc[rh][c][ri][0]);
                            acc[rh][c][ri][1] = fmaf(a, w.y, acc[rh][c][ri][1]);
                            acc[rh][c][ri][2] = fmaf(a, w.z, acc[rh][c][ri][2]);
                            acc[rh][c][ri][3] = fmaf(a, w.w, acc[rh][c][ri][3]);
                        }
                    }
                }
            }
        }
    }

    // epilogue: bias + activation + store
    float4 b4[2];
    b4[0] = *reinterpret_cast<const float4*>(&bias[tx * 4]);
    b4[1] = *reinterpret_cast<const float4*>(&bias[64 + tx * 4]);
    #pragma unroll
    for (int rh = 0; rh < 2; ++rh) {
        #pragma unroll
        for (int ri = 0; ri < 4; ++ri) {
            int row = base + rh * 64 + ty * 4 + ri;
            if (row < N) {
                #pragma unroll
                for (int c = 0; c < 2; ++c) {
                    float4 o;
                    o.x = acc[rh][c][ri][0] + b4[c].x;
                    o.y = acc[rh][c][ri][1] + b4[c].y;
                    o.z = acc[rh][c][ri][2] + b4[c].z;
                    o.w = acc[rh][c][ri][3] + b4[c].w;
                    if (RELU) {
                        o.x = fmaxf(o.x, 0.0f); o.y = fmaxf(o.y, 0.0f);
                        o.z = fmaxf(o.z, 0.0f); o.w = fmaxf(o.w, 0.0f);
                    }
                    float4* dst = reinterpret_cast<float4*>(
                        &out[(size_t)row * D + c * 64 + tx * 4]);
                    if (NT) nt_store_f4(o, dst);
                    else    *dst = o;
                }
            }
        }
    }
}

extern "C" void kernel_launch(void* const* d_in, const int* in_sizes, int n_in,
                              void* d_out, int out_size, void* d_ws, size_t ws_size,
                              hipStream_t stream) {
    const float* x   = (const float*)d_in[0];
    const int*   ei  = (const int*)d_in[1];
    const float* Wl0 = (const float*)d_in[2];
    const float* bl0 = (const float*)d_in[3];
    const float* Wr0 = (const float*)d_in[4];
    const float* Wl1 = (const float*)d_in[5];
    const float* bl1 = (const float*)d_in[6];
    const float* Wr1 = (const float*)d_in[7];
    const float* Wv  = (const float*)d_in[8];
    const float* bv  = (const float*)d_in[9];
    const float* Wt  = (const float*)d_in[10];
    const float* bt  = (const float*)d_in[11];

    const int N = in_sizes[0] / D;       // 100000
    const int E = in_sizes[1] / 2;       // 1600000
    const int* srcv = ei;
    const int* dstv = ei + E;

    float* out  = (float*)d_out;
    float* h    = out;                        // [0, N*D)      final output 0
    float* h1   = out + (size_t)N * D;        // scratch, later x_vision
    float* aggb = out + 2 * (size_t)N * D;    // scratch, later x_text

    const int nb   = (N + 4095) / 4096;
    const int nseg = (N + (1 << SEG_SHIFT) - 1) >> SEG_SHIFT;

    // CSR workspace: deg(N) | rowptr(N+1) | cursor(N) | csr(E) | bsum(nb) — ints
    size_t need = ((size_t)(3 * N + 1) + (size_t)E + (size_t)nb) * sizeof(int);
    int* wsI = (ws_size >= need) ? (int*)d_ws
                                 : (int*)h;   // fallback: h region is free until layer-1 gemm
    int* degI   = wsI;
    int* rowptr = wsI + N;
    int* cursor = wsI + 2 * N + 1;
    int* csr    = wsI + 3 * N + 1;
    int* bsum   = wsI + 3 * N + 1 + E;

    (void)hipMemsetAsync(degI, 0, (size_t)N * sizeof(int), stream);
    k_deg <<<2048, 256, 0, stream>>>(dstv, degI, E, nseg);
    k_scan_a<<<nb, 1024, 0, stream>>>(degI, rowptr, bsum, N);
    k_scan_b<<<nb, 1024, 0, stream>>>(rowptr, cursor, bsum, N, nb);
    k_fill<<<2048, 256, 0, stream>>>(srcv, dstv, cursor, csr, E, nseg);

    const int agg_blocks  = (int)(((size_t)N * 64 + 255) / 256);
    const int gemm_blocks = (N + 127) / 128;

    // ---- layer 0 ----
    k_agg<<<agg_blocks, 256, 0, stream>>>(rowptr, csr, x, aggb, N);
    k_gemm<true, 2, false><<<gemm_blocks, 256, 0, stream>>>(aggb, x, Wl0, Wr0, bl0, h1, N);

    // ---- layer 1 ----
    k_agg<<<agg_blocks, 256, 0, stream>>>(rowptr, csr, h1, aggb, N);
    k_gemm<false, 2, false><<<gemm_blocks, 256, 0, stream>>>(aggb, h1, Wl1, Wr1, bl1, h, N);

    // ---- heads: xv = relu(h@Wv^T+bv), xt = relu(h@Wt^T+bt) ----
    k_gemm<true, 1, true><<<gemm_blocks, 256, 0, stream>>>(h, nullptr, Wv, nullptr, bv,
                                                           out + (size_t)N * D, N);
    k_gemm<true, 1, true><<<gemm_blocks, 256, 0, stream>>>(h, nullptr, Wt, nullptr, bt,
                                                           out + 2 * (size_t)N * D, N);
}

// Round 7
// 688.437 us; speedup vs baseline: 2.6532x; 1.0041x over previous
//
#include <hip/hip_runtime.h>

#define D 128
#define SEG_SHIFT 14              // 16384-node atomic/scatter window (~0.9MB csr/pass)

typedef float nfloat4 __attribute__((ext_vector_type(4)));

__device__ __forceinline__ void nt_store_f4(const float4& v, float4* p) {
    nfloat4 nv;
    nv.x = v.x; nv.y = v.y; nv.z = v.z; nv.w = v.w;
    __builtin_nontemporal_store(nv, reinterpret_cast<nfloat4*>(p));
}

// ---------------- segmented degree histogram ----------------
__global__ __launch_bounds__(256) void k_deg(const int* __restrict__ dst,
                                             int* __restrict__ deg, int E, int nseg) {
    const int stride = gridDim.x * blockDim.x;
    const int t0 = blockIdx.x * blockDim.x + threadIdx.x;
    for (int seg = 0; seg < nseg; ++seg) {
        const int lo = seg << SEG_SHIFT, hi = lo + (1 << SEG_SHIFT);
        for (int e = t0; e < E; e += stride) {
            int d = dst[e];
            if (d >= lo && d < hi) atomicAdd(&deg[d], 1);
        }
    }
}

// ---------------- multi-block exclusive scan, phase A ----------------
__global__ __launch_bounds__(1024) void k_scan_a(const int* __restrict__ deg,
                                                 int* __restrict__ rowptr,
                                                 int* __restrict__ bsum, int N) {
    __shared__ int wsum[16];
    __shared__ int wscan[16];
    const int tid = threadIdx.x, lane = tid & 63, wid = tid >> 6;
    const int i = blockIdx.x * 4096 + tid * 4;
    int4 v = *reinterpret_cast<const int4*>(&deg[i]);
    int v0 = (i     < N) ? v.x : 0;
    int v1 = (i + 1 < N) ? v.y : 0;
    int v2 = (i + 2 < N) ? v.z : 0;
    int v3 = (i + 3 < N) ? v.w : 0;
    const int t = v0 + v1 + v2 + v3;
    int x = t;
    #pragma unroll
    for (int off = 1; off < 64; off <<= 1) {
        int u = __shfl_up(x, off);
        if (lane >= off) x += u;
    }
    if (lane == 63) wsum[wid] = x;
    __syncthreads();
    if (wid == 0) {
        int s = (lane < 16) ? wsum[lane] : 0;
        #pragma unroll
        for (int off = 1; off < 16; off <<= 1) {
            int u = __shfl_up(s, off);
            if (lane >= off) s += u;
        }
        if (lane < 16) wscan[lane] = s;
    }
    __syncthreads();
    int excl = x - t + ((wid > 0) ? wscan[wid - 1] : 0);
    if (i     < N) rowptr[i]     = excl;
    if (i + 1 < N) rowptr[i + 1] = excl + v0;
    if (i + 2 < N) rowptr[i + 2] = excl + v0 + v1;
    if (i + 3 < N) rowptr[i + 3] = excl + v0 + v1 + v2;
    if (tid == 0) bsum[blockIdx.x] = wscan[15];
}

// ---------------- scan phase B: add block offsets, seed cursor ----------------
__global__ __launch_bounds__(1024) void k_scan_b(int* __restrict__ rowptr,
                                                 int* __restrict__ cursor,
                                                 const int* __restrict__ bsum,
                                                 int N, int nb) {
    __shared__ int s_off;
    if (threadIdx.x == 0) {
        int o = 0;
        for (int b = 0; b < (int)blockIdx.x; ++b) o += bsum[b];
        s_off = o;
        if ((int)blockIdx.x == nb - 1) rowptr[N] = o + bsum[nb - 1];
    }
    __syncthreads();
    const int off = s_off;
    const int i = blockIdx.x * 4096 + threadIdx.x * 4;
    if (i + 3 < N) {
        int4 r = *reinterpret_cast<const int4*>(&rowptr[i]);
        r.x += off; r.y += off; r.z += off; r.w += off;
        *reinterpret_cast<int4*>(&rowptr[i]) = r;
        *reinterpret_cast<int4*>(&cursor[i]) = r;
    } else {
        #pragma unroll
        for (int k = 0; k < 4; ++k) {
            int ii = i + k;
            if (ii < N) {
                int r = rowptr[ii] + off;
                rowptr[ii] = r;
                cursor[ii] = r;
            }
        }
    }
}

// ---------------- segmented CSR fill ----------------
__global__ __launch_bounds__(256) void k_fill(const int* __restrict__ src,
                                              const int* __restrict__ dst,
                                              int* __restrict__ cursor,
                                              int* __restrict__ csr, int E, int nseg) {
    const int stride = gridDim.x * blockDim.x;
    const int t0 = blockIdx.x * blockDim.x + threadIdx.x;
    for (int seg = 0; seg < nseg; ++seg) {
        const int lo = seg << SEG_SHIFT, hi = lo + (1 << SEG_SHIFT);
        for (int e = t0; e < E; e += stride) {
            int d = dst[e];
            if (d >= lo && d < hi) {
                int p = atomicAdd(&cursor[d], 1);
                csr[p] = src[e];
            }
        }
    }
}

// ---------------- gather-mean aggregation ----------------
// One wave per dst node. Half-wave per source row; 8 gather chains in flight
// (8 x 1KB per wave) to probe the latency vs L2-miss-BW limit.
__global__ __launch_bounds__(512) void k_agg(const int* __restrict__ rowptr,
                                             const int* __restrict__ csr,
                                             const float* __restrict__ xin,
                                             float* __restrict__ agg, int N) {
    int w = (int)((blockIdx.x * 512u + threadIdx.x) >> 6);
    int lane = threadIdx.x & 63;
    if (w >= N) return;
    int s0 = rowptr[w], s1 = rowptr[w + 1];
    const int half = lane >> 5;
    const int c4 = lane & 31;                 // float4 index within row
    const float4* xin4 = reinterpret_cast<const float4*>(xin);
    float4 a0 = make_float4(0.f, 0.f, 0.f, 0.f);
    float4 a1 = make_float4(0.f, 0.f, 0.f, 0.f);
    float4 a2 = make_float4(0.f, 0.f, 0.f, 0.f);
    float4 a3 = make_float4(0.f, 0.f, 0.f, 0.f);

    for (int p = s0; p < s1; p += 64) {
        int m = s1 - p; if (m > 64) m = 64;
        int my = (p + lane < s1) ? csr[p + lane] : 0;
        int j = 0;
        for (; j + 15 < m; j += 16) {
            int r0 = __shfl(my, j +      half);
            int r1 = __shfl(my, j + 2  + half);
            int r2 = __shfl(my, j + 4  + half);
            int r3 = __shfl(my, j + 6  + half);
            int r4 = __shfl(my, j + 8  + half);
            int r5 = __shfl(my, j + 10 + half);
            int r6 = __shfl(my, j + 12 + half);
            int r7 = __shfl(my, j + 14 + half);
            float4 v0 = xin4[(size_t)r0 * 32 + c4];
            float4 v1 = xin4[(size_t)r1 * 32 + c4];
            float4 v2 = xin4[(size_t)r2 * 32 + c4];
            float4 v3 = xin4[(size_t)r3 * 32 + c4];
            float4 v4 = xin4[(size_t)r4 * 32 + c4];
            float4 v5 = xin4[(size_t)r5 * 32 + c4];
            float4 v6 = xin4[(size_t)r6 * 32 + c4];
            float4 v7 = xin4[(size_t)r7 * 32 + c4];
            a0.x += v0.x; a0.y += v0.y; a0.z += v0.z; a0.w += v0.w;
            a1.x += v1.x; a1.y += v1.y; a1.z += v1.z; a1.w += v1.w;
            a2.x += v2.x; a2.y += v2.y; a2.z += v2.z; a2.w += v2.w;
            a3.x += v3.x; a3.y += v3.y; a3.z += v3.z; a3.w += v3.w;
            a0.x += v4.x; a0.y += v4.y; a0.z += v4.z; a0.w += v4.w;
            a1.x += v5.x; a1.y += v5.y; a1.z += v5.z; a1.w += v5.w;
            a2.x += v6.x; a2.y += v6.y; a2.z += v6.z; a2.w += v6.w;
            a3.x += v7.x; a3.y += v7.y; a3.z += v7.z; a3.w += v7.w;
        }
        for (; j + 7 < m; j += 8) {
            int r0 = __shfl(my, j +     half);
            int r1 = __shfl(my, j + 2 + half);
            int r2 = __shfl(my, j + 4 + half);
            int r3 = __shfl(my, j + 6 + half);
            float4 v0 = xin4[(size_t)r0 * 32 + c4];
            float4 v1 = xin4[(size_t)r1 * 32 + c4];
            float4 v2 = xin4[(size_t)r2 * 32 + c4];
            float4 v3 = xin4[(size_t)r3 * 32 + c4];
            a0.x += v0.x; a0.y += v0.y; a0.z += v0.z; a0.w += v0.w;
            a1.x += v1.x; a1.y += v1.y; a1.z += v1.z; a1.w += v1.w;
            a2.x += v2.x; a2.y += v2.y; a2.z += v2.z; a2.w += v2.w;
            a3.x += v3.x; a3.y += v3.y; a3.z += v3.z; a3.w += v3.w;
        }
        for (; j + 1 < m; j += 2) {
            int r0 = __shfl(my, j + half);
            float4 v0 = xin4[(size_t)r0 * 32 + c4];
            a0.x += v0.x; a0.y += v0.y; a0.z += v0.z; a0.w += v0.w;
        }
        if (j < m) {
            int r0 = __shfl(my, j);
            float4 v0 = xin4[(size_t)r0 * 32 + c4];
            if (half == 0) {
                a0.x += v0.x; a0.y += v0.y; a0.z += v0.z; a0.w += v0.w;
            }
        }
    }

    float4 s;
    s.x = (a0.x + a1.x) + (a2.x + a3.x);
    s.y = (a0.y + a1.y) + (a2.y + a3.y);
    s.z = (a0.z + a1.z) + (a2.z + a3.z);
    s.w = (a0.w + a1.w) + (a2.w + a3.w);
    s.x += __shfl_xor(s.x, 32);
    s.y += __shfl_xor(s.y, 32);
    s.z += __shfl_xor(s.z, 32);
    s.w += __shfl_xor(s.w, 32);

    float inv = 1.0f / fmaxf((float)(s1 - s0), 1.0f);
    if (half == 0) {
        float4 o = make_float4(s.x * inv, s.y * inv, s.z * inv, s.w * inv);
        nt_store_f4(o, &reinterpret_cast<float4*>(agg)[(size_t)w * 32 + c4]);
    }
}

// ---------------- register-tiled SGEMM (static schedule) ----------------
// out[i,j] = act( sum_m sum_k A_m[i,k] * W_m[j,k]  + bias[j] )
template <bool RELU, int NMAT, bool NT>
__global__ __launch_bounds__(256) void k_gemm(
    const float* __restrict__ A0, const float* __restrict__ A1,
    const float* __restrict__ W0, const float* __restrict__ W1,
    const float* __restrict__ bias,
    float* __restrict__ out, int N)
{
    __shared__ float sA[128 * 36];   // rows x (BK=32 + pad4)   = 18 KB
    __shared__ float sW[32 * 132];   // k x (128 cols + pad4)   = 16.5 KB

    const int tid = threadIdx.x;
    const int tx  = tid & 15;
    const int ty  = tid >> 4;
    const int base = blockIdx.x * 128;

    float acc[2][2][4][4];
    #pragma unroll
    for (int a = 0; a < 2; ++a)
        #pragma unroll
        for (int b = 0; b < 2; ++b)
            #pragma unroll
            for (int i = 0; i < 4; ++i)
                #pragma unroll
                for (int j = 0; j < 4; ++j)
                    acc[a][b][i][j] = 0.0f;

    const int NCH = NMAT * 4;
    for (int c_i = 0; c_i < NCH; ++c_i) {
        const float* Asrc = (NMAT == 2 && c_i >= 4) ? A1 : A0;
        const float* Wsrc = (NMAT == 2 && c_i >= 4) ? W1 : W0;
        const int kc = (c_i & 3) * 32;

        __syncthreads();

        #pragma unroll
        for (int it = 0; it < 4; ++it) {
            int idx = it * 256 + tid;
            int row = idx >> 3, kq = idx & 7;
            int grow = base + row;
            if (grow >= N) grow = N - 1;
            float4 v = *reinterpret_cast<const float4*>(
                &Asrc[(size_t)grow * D + kc + kq * 4]);
            *reinterpret_cast<float4*>(&sA[row * 36 + kq * 4]) = v;
        }
        #pragma unroll
        for (int it = 0; it < 4; ++it) {
            int idx = it * 256 + tid;
            int j = idx >> 3, kq = idx & 7;
            float4 v = *reinterpret_cast<const float4*>(&Wsrc[j * D + kc + kq * 4]);
            sW[(kq * 4 + 0) * 132 + j] = v.x;
            sW[(kq * 4 + 1) * 132 + j] = v.y;
            sW[(kq * 4 + 2) * 132 + j] = v.z;
            sW[(kq * 4 + 3) * 132 + j] = v.w;
        }
        __syncthreads();

        #pragma unroll
        for (int kk = 0; kk < 32; kk += 4) {
            float4 av[2][4];
            #pragma unroll
            for (int rh = 0; rh < 2; ++rh)
                #pragma unroll
                for (int ri = 0; ri < 4; ++ri)
                    av[rh][ri] = *reinterpret_cast<const float4*>(
                        &sA[(rh * 64 + ty * 4 + ri) * 36 + kk]);
            float4 wv[4][2];
            #pragma unroll
            for (int kq = 0; kq < 4; ++kq)
                #pragma unroll
                for (int c = 0; c < 2; ++c)
                    wv[kq][c] = *reinterpret_cast<const float4*>(
                        &sW[(kk + kq) * 132 + c * 64 + tx * 4]);
            #pragma unroll
            for (int kq = 0; kq < 4; ++kq) {
                #pragma unroll
                for (int rh = 0; rh < 2; ++rh) {
                    #pragma unroll
                    for (int ri = 0; ri < 4; ++ri) {
                        float a = reinterpret_cast<const float*>(&av[rh][ri])[kq];
                        #pragma unroll
                        for (int c = 0; c < 2; ++c) {
                            float4 w = wv[kq][c];
                            acc[rh][c][ri][0] = fmaf(a, w.x, acc[rh][c][ri][0]);
                            acc[rh][c][ri][1] = fmaf(a, w.y, acc[rh][c][ri][1]);
                            acc[rh][c][ri][2] = fmaf(a, w.z, acc[rh][c][ri][2]);
                            acc[rh][c][ri][3] = fmaf(a, w.w, acc[rh][c][ri][3]);
                        }
                    }
                }
            }
        }
    }

    float4 b4[2];
    b4[0] = *reinterpret_cast<const float4*>(&bias[tx * 4]);
    b4[1] = *reinterpret_cast<const float4*>(&bias[64 + tx * 4]);
    #pragma unroll
    for (int rh = 0; rh < 2; ++rh) {
        #pragma unroll
        for (int ri = 0; ri < 4; ++ri) {
            int row = base + rh * 64 + ty * 4 + ri;
            if (row < N) {
                #pragma unroll
                for (int c = 0; c < 2; ++c) {
                    float4 o;
                    o.x = acc[rh][c][ri][0] + b4[c].x;
                    o.y = acc[rh][c][ri][1] + b4[c].y;
                    o.z = acc[rh][c][ri][2] + b4[c].z;
                    o.w = acc[rh][c][ri][3] + b4[c].w;
                    if (RELU) {
                        o.x = fmaxf(o.x, 0.0f); o.y = fmaxf(o.y, 0.0f);
                        o.z = fmaxf(o.z, 0.0f); o.w = fmaxf(o.w, 0.0f);
                    }
                    float4* dst = reinterpret_cast<float4*>(
                        &out[(size_t)row * D + c * 64 + tx * 4]);
                    if (NT) nt_store_f4(o, dst);
                    else    *dst = o;
                }
            }
        }
    }
}

// ---------------- fused dual-head GEMM ----------------
// 128 rows x 256 cols (colhalf 0 -> xv via Wv, colhalf 1 -> xt via Wt).
// 512 threads, 8x8 micro-tile, h tile staged ONCE per chunk for both heads.
__global__ __launch_bounds__(512) void k_head2(
    const float* __restrict__ h,
    const float* __restrict__ Wv, const float* __restrict__ bv,
    const float* __restrict__ Wt, const float* __restrict__ bt,
    float* __restrict__ xv, float* __restrict__ xt, int N)
{
    __shared__ float sA [128 * 36];  // 18 KB
    __shared__ float sWv[32 * 132];  // 16.5 KB
    __shared__ float sWt[32 * 132];  // 16.5 KB

    const int tid = threadIdx.x;
    const int tx  = tid & 31;        // 32 col groups x 4 cols = 128 cols per head
    const int ty  = tid >> 5;        // 16 row groups
    const int base = blockIdx.x * 128;

    float acc[2][2][4][4];           // [rowhalf][head][ri][ci]
    #pragma unroll
    for (int a = 0; a < 2; ++a)
        #pragma unroll
        for (int b = 0; b < 2; ++b)
            #pragma unroll
            for (int i = 0; i < 4; ++i)
                #pragma unroll
                for (int j = 0; j < 4; ++j)
                    acc[a][b][i][j] = 0.0f;

    for (int c_i = 0; c_i < 4; ++c_i) {
        const int kc = c_i * 32;
        __syncthreads();

        // stage h chunk: 1024 float4, 2 per thread
        #pragma unroll
        for (int it = 0; it < 2; ++it) {
            int idx = it * 512 + tid;
            int row = idx >> 3, kq = idx & 7;
            int grow = base + row;
            if (grow >= N) grow = N - 1;
            float4 v = *reinterpret_cast<const float4*>(
                &h[(size_t)grow * D + kc + kq * 4]);
            *reinterpret_cast<float4*>(&sA[row * 36 + kq * 4]) = v;
        }
        // stage Wv, Wt chunks transposed
        #pragma unroll
        for (int it = 0; it < 2; ++it) {
            int idx = it * 512 + tid;
            int j = idx >> 3, kq = idx & 7;
            float4 v = *reinterpret_cast<const float4*>(&Wv[j * D + kc + kq * 4]);
            sWv[(kq * 4 + 0) * 132 + j] = v.x;
            sWv[(kq * 4 + 1) * 132 + j] = v.y;
            sWv[(kq * 4 + 2) * 132 + j] = v.z;
            sWv[(kq * 4 + 3) * 132 + j] = v.w;
            float4 u = *reinterpret_cast<const float4*>(&Wt[j * D + kc + kq * 4]);
            sWt[(kq * 4 + 0) * 132 + j] = u.x;
            sWt[(kq * 4 + 1) * 132 + j] = u.y;
            sWt[(kq * 4 + 2) * 132 + j] = u.z;
            sWt[(kq * 4 + 3) * 132 + j] = u.w;
        }
        __syncthreads();

        #pragma unroll
        for (int kk = 0; kk < 32; kk += 4) {
            float4 av[2][4];
            #pragma unroll
            for (int rh = 0; rh < 2; ++rh)
                #pragma unroll
                for (int ri = 0; ri < 4; ++ri)
                    av[rh][ri] = *reinterpret_cast<const float4*>(
                        &sA[(rh * 64 + ty * 4 + ri) * 36 + kk]);
            float4 wv[4][2];   // [kq][head]
            #pragma unroll
            for (int kq = 0; kq < 4; ++kq) {
                wv[kq][0] = *reinterpret_cast<const float4*>(
                    &sWv[(kk + kq) * 132 + tx * 4]);
                wv[kq][1] = *reinterpret_cast<const float4*>(
                    &sWt[(kk + kq) * 132 + tx * 4]);
            }
            #pragma unroll
            for (int kq = 0; kq < 4; ++kq) {
                #pragma unroll
                for (int rh = 0; rh < 2; ++rh) {
                    #pragma unroll
                    for (int ri = 0; ri < 4; ++ri) {
                        float a = reinterpret_cast<const float*>(&av[rh][ri])[kq];
                        #pragma unroll
                        for (int c = 0; c < 2; ++c) {
                            float4 w = wv[kq][c];
                            acc[rh][c][ri][0] = fmaf(a, w.x, acc[rh][c][ri][0]);
                            acc[rh][c][ri][1] = fmaf(a, w.y, acc[rh][c][ri][1]);
                            acc[rh][c][ri][2] = fmaf(a, w.z, acc[rh][c][ri][2]);
                            acc[rh][c][ri][3] = fmaf(a, w.w, acc[rh][c][ri][3]);
                        }
                    }
                }
            }
        }
    }

    float4 bv4 = *reinterpret_cast<const float4*>(&bv[tx * 4]);
    float4 bt4 = *reinterpret_cast<const float4*>(&bt[tx * 4]);
    #pragma unroll
    for (int rh = 0; rh < 2; ++rh) {
        #pragma unroll
        for (int ri = 0; ri < 4; ++ri) {
            int row = base + rh * 64 + ty * 4 + ri;
            if (row < N) {
                float4 o;
                o.x = fmaxf(acc[rh][0][ri][0] + bv4.x, 0.0f);
                o.y = fmaxf(acc[rh][0][ri][1] + bv4.y, 0.0f);
                o.z = fmaxf(acc[rh][0][ri][2] + bv4.z, 0.0f);
                o.w = fmaxf(acc[rh][0][ri][3] + bv4.w, 0.0f);
                nt_store_f4(o, reinterpret_cast<float4*>(&xv[(size_t)row * D + tx * 4]));
                float4 q;
                q.x = fmaxf(acc[rh][1][ri][0] + bt4.x, 0.0f);
                q.y = fmaxf(acc[rh][1][ri][1] + bt4.y, 0.0f);
                q.z = fmaxf(acc[rh][1][ri][2] + bt4.z, 0.0f);
                q.w = fmaxf(acc[rh][1][ri][3] + bt4.w, 0.0f);
                nt_store_f4(q, reinterpret_cast<float4*>(&xt[(size_t)row * D + tx * 4]));
            }
        }
    }
}

extern "C" void kernel_launch(void* const* d_in, const int* in_sizes, int n_in,
                              void* d_out, int out_size, void* d_ws, size_t ws_size,
                              hipStream_t stream) {
    const float* x   = (const float*)d_in[0];
    const int*   ei  = (const int*)d_in[1];
    const float* Wl0 = (const float*)d_in[2];
    const float* bl0 = (const float*)d_in[3];
    const float* Wr0 = (const float*)d_in[4];
    const float* Wl1 = (const float*)d_in[5];
    const float* bl1 = (const float*)d_in[6];
    const float* Wr1 = (const float*)d_in[7];
    const float* Wv  = (const float*)d_in[8];
    const float* bv  = (const float*)d_in[9];
    const float* Wt  = (const float*)d_in[10];
    const float* bt  = (const float*)d_in[11];

    const int N = in_sizes[0] / D;       // 100000
    const int E = in_sizes[1] / 2;       // 1600000
    const int* srcv = ei;
    const int* dstv = ei + E;

    float* out  = (float*)d_out;
    float* h    = out;                        // [0, N*D)      final output 0
    float* h1   = out + (size_t)N * D;        // scratch, later x_vision
    float* aggb = out + 2 * (size_t)N * D;    // scratch, later x_text

    const int nb   = (N + 4095) / 4096;
    const int nseg = (N + (1 << SEG_SHIFT) - 1) >> SEG_SHIFT;

    // CSR workspace: deg(N) | rowptr(N+1) | cursor(N) | csr(E) | bsum(nb) — ints
    size_t need = ((size_t)(3 * N + 1) + (size_t)E + (size_t)nb) * sizeof(int);
    int* wsI = (ws_size >= need) ? (int*)d_ws
                                 : (int*)h;   // fallback: h region is free until layer-1 gemm
    int* degI   = wsI;
    int* rowptr = wsI + N;
    int* cursor = wsI + 2 * N + 1;
    int* csr    = wsI + 3 * N + 1;
    int* bsum   = wsI + 3 * N + 1 + E;

    (void)hipMemsetAsync(degI, 0, (size_t)N * sizeof(int), stream);
    k_deg <<<2048, 256, 0, stream>>>(dstv, degI, E, nseg);
    k_scan_a<<<nb, 1024, 0, stream>>>(degI, rowptr, bsum, N);
    k_scan_b<<<nb, 1024, 0, stream>>>(rowptr, cursor, bsum, N, nb);
    k_fill<<<2048, 256, 0, stream>>>(srcv, dstv, cursor, csr, E, nseg);

    const int agg_blocks  = (int)(((size_t)N * 64 + 511) / 512);
    const int gemm_blocks = (N + 127) / 128;

    // ---- layer 0 ----
    k_agg<<<agg_blocks, 512, 0, stream>>>(rowptr, csr, x, aggb, N);
    k_gemm<true, 2, false><<<gemm_blocks, 256, 0, stream>>>(aggb, x, Wl0, Wr0, bl0, h1, N);

    // ---- layer 1 ----
    k_agg<<<agg_blocks, 512, 0, stream>>>(rowptr, csr, h1, aggb, N);
    k_gemm<false, 2, false><<<gemm_blocks, 256, 0, stream>>>(aggb, h1, Wl1, Wr1, bl1, h, N);

    // ---- fused heads ----
    k_head2<<<gemm_blocks, 512, 0, stream>>>(h, Wv, bv, Wt, bt,
                                             out + (size_t)N * D,
                                             out + 2 * (size_t)N * D, N);
}

// Round 8
// 670.505 us; speedup vs baseline: 2.7241x; 1.0267x over previous
//
#include <hip/hip_runtime.h>
#include <hip/hip_fp16.h>

#define D 128
#define SEG_SHIFT 15              // 32768-node atomic window; 4 passes over edges

typedef float nfloat4 __attribute__((ext_vector_type(4)));

__device__ __forceinline__ void nt_store_f4(const float4& v, float4* p) {
    nfloat4 nv;
    nv.x = v.x; nv.y = v.y; nv.z = v.z; nv.w = v.w;
    __builtin_nontemporal_store(nv, reinterpret_cast<nfloat4*>(p));
}

// ---------------- fp32 -> fp16 row cast (for gather traffic halving) ----------------
__global__ __launch_bounds__(256) void k_cvt(const float* __restrict__ in,
                                             __half* __restrict__ out, int n8) {
    int i = blockIdx.x * 256 + threadIdx.x;
    const int stride = gridDim.x * 256;
    for (; i < n8; i += stride) {
        float4 a = reinterpret_cast<const float4*>(in)[(size_t)i * 2];
        float4 b = reinterpret_cast<const float4*>(in)[(size_t)i * 2 + 1];
        __half2 h0 = __floats2half2_rn(a.x, a.y);
        __half2 h1 = __floats2half2_rn(a.z, a.w);
        __half2 h2 = __floats2half2_rn(b.x, b.y);
        __half2 h3 = __floats2half2_rn(b.z, b.w);
        int4 o;
        o.x = *reinterpret_cast<int*>(&h0);
        o.y = *reinterpret_cast<int*>(&h1);
        o.z = *reinterpret_cast<int*>(&h2);
        o.w = *reinterpret_cast<int*>(&h3);
        reinterpret_cast<int4*>(out)[i] = o;
    }
}

// ---------------- segmented degree histogram ----------------
__global__ __launch_bounds__(256) void k_deg(const int* __restrict__ dst,
                                             int* __restrict__ deg, int E, int nseg) {
    const int stride = gridDim.x * blockDim.x;
    const int t0 = blockIdx.x * blockDim.x + threadIdx.x;
    for (int seg = 0; seg < nseg; ++seg) {
        const int lo = seg << SEG_SHIFT, hi = lo + (1 << SEG_SHIFT);
        for (int e = t0; e < E; e += stride) {
            int d = __builtin_nontemporal_load(&dst[e]);
            if (d >= lo && d < hi) atomicAdd(&deg[d], 1);
        }
    }
}

// ---------------- multi-block exclusive scan, phase A ----------------
__global__ __launch_bounds__(1024) void k_scan_a(const int* __restrict__ deg,
                                                 int* __restrict__ rowptr,
                                                 int* __restrict__ bsum, int N) {
    __shared__ int wsum[16];
    __shared__ int wscan[16];
    const int tid = threadIdx.x, lane = tid & 63, wid = tid >> 6;
    const int i = blockIdx.x * 4096 + tid * 4;
    int4 v = *reinterpret_cast<const int4*>(&deg[i]);
    int v0 = (i     < N) ? v.x : 0;
    int v1 = (i + 1 < N) ? v.y : 0;
    int v2 = (i + 2 < N) ? v.z : 0;
    int v3 = (i + 3 < N) ? v.w : 0;
    const int t = v0 + v1 + v2 + v3;
    int x = t;
    #pragma unroll
    for (int off = 1; off < 64; off <<= 1) {
        int u = __shfl_up(x, off);
        if (lane >= off) x += u;
    }
    if (lane == 63) wsum[wid] = x;
    __syncthreads();
    if (wid == 0) {
        int s = (lane < 16) ? wsum[lane] : 0;
        #pragma unroll
        for (int off = 1; off < 16; off <<= 1) {
            int u = __shfl_up(s, off);
            if (lane >= off) s += u;
        }
        if (lane < 16) wscan[lane] = s;
    }
    __syncthreads();
    int excl = x - t + ((wid > 0) ? wscan[wid - 1] : 0);
    if (i     < N) rowptr[i]     = excl;
    if (i + 1 < N) rowptr[i + 1] = excl + v0;
    if (i + 2 < N) rowptr[i + 2] = excl + v0 + v1;
    if (i + 3 < N) rowptr[i + 3] = excl + v0 + v1 + v2;
    if (tid == 0) bsum[blockIdx.x] = wscan[15];
}

// ---------------- scan phase B: add block offsets, seed cursor ----------------
__global__ __launch_bounds__(1024) void k_scan_b(int* __restrict__ rowptr,
                                                 int* __restrict__ cursor,
                                                 const int* __restrict__ bsum,
                                                 int N, int nb) {
    __shared__ int s_off;
    if (threadIdx.x == 0) {
        int o = 0;
        for (int b = 0; b < (int)blockIdx.x; ++b) o += bsum[b];
        s_off = o;
        if ((int)blockIdx.x == nb - 1) rowptr[N] = o + bsum[nb - 1];
    }
    __syncthreads();
    const int off = s_off;
    const int i = blockIdx.x * 4096 + threadIdx.x * 4;
    if (i + 3 < N) {
        int4 r = *reinterpret_cast<const int4*>(&rowptr[i]);
        r.x += off; r.y += off; r.z += off; r.w += off;
        *reinterpret_cast<int4*>(&rowptr[i]) = r;
        *reinterpret_cast<int4*>(&cursor[i]) = r;
    } else {
        #pragma unroll
        for (int k = 0; k < 4; ++k) {
            int ii = i + k;
            if (ii < N) {
                int r = rowptr[ii] + off;
                rowptr[ii] = r;
                cursor[ii] = r;
            }
        }
    }
}

// ---------------- segmented CSR fill ----------------
__global__ __launch_bounds__(256) void k_fill(const int* __restrict__ src,
                                              const int* __restrict__ dst,
                                              int* __restrict__ cursor,
                                              int* __restrict__ csr, int E, int nseg) {
    const int stride = gridDim.x * blockDim.x;
    const int t0 = blockIdx.x * blockDim.x + threadIdx.x;
    for (int seg = 0; seg < nseg; ++seg) {
        const int lo = seg << SEG_SHIFT, hi = lo + (1 << SEG_SHIFT);
        for (int e = t0; e < E; e += stride) {
            int d = __builtin_nontemporal_load(&dst[e]);
            if (d >= lo && d < hi) {
                int p = atomicAdd(&cursor[d], 1);
                csr[p] = __builtin_nontemporal_load(&src[e]);
            }
        }
    }
}

// ---------------- gather-mean aggregation (fp16 rows, fp32 accumulate) ----------------
// One wave per dst node. Half-wave per source row: 32 lanes x 8B (4 halfs) = 256B row.
// 8 load chains -> 16 edges in flight per unrolled iter.
__device__ __forceinline__ void acc_add(float4& a, int2 raw) {
    __half2 h01 = *reinterpret_cast<const __half2*>(&raw.x);
    __half2 h23 = *reinterpret_cast<const __half2*>(&raw.y);
    float2 f01 = __half22float2(h01);
    float2 f23 = __half22float2(h23);
    a.x += f01.x; a.y += f01.y; a.z += f23.x; a.w += f23.y;
}

__global__ __launch_bounds__(512) void k_agg(const int* __restrict__ rowptr,
                                             const int* __restrict__ csr,
                                             const __half* __restrict__ xh,
                                             float* __restrict__ agg, int N) {
    int w = (int)((blockIdx.x * 512u + threadIdx.x) >> 6);
    int lane = threadIdx.x & 63;
    if (w >= N) return;
    int s0 = rowptr[w], s1 = rowptr[w + 1];
    const int half = lane >> 5;
    const int c4 = lane & 31;                 // 8B chunk index within row (dims 4*c4..)
    const int2* xh2 = reinterpret_cast<const int2*>(xh);
    float4 a0 = make_float4(0.f, 0.f, 0.f, 0.f);
    float4 a1 = make_float4(0.f, 0.f, 0.f, 0.f);
    float4 a2 = make_float4(0.f, 0.f, 0.f, 0.f);
    float4 a3 = make_float4(0.f, 0.f, 0.f, 0.f);

    for (int p = s0; p < s1; p += 64) {
        int m = s1 - p; if (m > 64) m = 64;
        int my = (p + lane < s1) ? csr[p + lane] : 0;
        int j = 0;
        for (; j + 15 < m; j += 16) {
            int r0 = __shfl(my, j +      half);
            int r1 = __shfl(my, j + 2  + half);
            int r2 = __shfl(my, j + 4  + half);
            int r3 = __shfl(my, j + 6  + half);
            int r4 = __shfl(my, j + 8  + half);
            int r5 = __shfl(my, j + 10 + half);
            int r6 = __shfl(my, j + 12 + half);
            int r7 = __shfl(my, j + 14 + half);
            int2 v0 = xh2[(size_t)r0 * 32 + c4];
            int2 v1 = xh2[(size_t)r1 * 32 + c4];
            int2 v2 = xh2[(size_t)r2 * 32 + c4];
            int2 v3 = xh2[(size_t)r3 * 32 + c4];
            int2 v4 = xh2[(size_t)r4 * 32 + c4];
            int2 v5 = xh2[(size_t)r5 * 32 + c4];
            int2 v6 = xh2[(size_t)r6 * 32 + c4];
            int2 v7 = xh2[(size_t)r7 * 32 + c4];
            acc_add(a0, v0); acc_add(a1, v1); acc_add(a2, v2); acc_add(a3, v3);
            acc_add(a0, v4); acc_add(a1, v5); acc_add(a2, v6); acc_add(a3, v7);
        }
        for (; j + 7 < m; j += 8) {
            int r0 = __shfl(my, j +     half);
            int r1 = __shfl(my, j + 2 + half);
            int r2 = __shfl(my, j + 4 + half);
            int r3 = __shfl(my, j + 6 + half);
            int2 v0 = xh2[(size_t)r0 * 32 + c4];
            int2 v1 = xh2[(size_t)r1 * 32 + c4];
            int2 v2 = xh2[(size_t)r2 * 32 + c4];
            int2 v3 = xh2[(size_t)r3 * 32 + c4];
            acc_add(a0, v0); acc_add(a1, v1); acc_add(a2, v2); acc_add(a3, v3);
        }
        for (; j + 1 < m; j += 2) {
            int r0 = __shfl(my, j + half);
            int2 v0 = xh2[(size_t)r0 * 32 + c4];
            acc_add(a0, v0);
        }
        if (j < m) {
            int r0 = __shfl(my, j);
            int2 v0 = xh2[(size_t)r0 * 32 + c4];
            if (half == 0) acc_add(a0, v0);
        }
    }

    float4 s;
    s.x = (a0.x + a1.x) + (a2.x + a3.x);
    s.y = (a0.y + a1.y) + (a2.y + a3.y);
    s.z = (a0.z + a1.z) + (a2.z + a3.z);
    s.w = (a0.w + a1.w) + (a2.w + a3.w);
    s.x += __shfl_xor(s.x, 32);
    s.y += __shfl_xor(s.y, 32);
    s.z += __shfl_xor(s.z, 32);
    s.w += __shfl_xor(s.w, 32);

    float inv = 1.0f / fmaxf((float)(s1 - s0), 1.0f);
    if (half == 0) {
        float4 o = make_float4(s.x * inv, s.y * inv, s.z * inv, s.w * inv);
        nt_store_f4(o, &reinterpret_cast<float4*>(agg)[(size_t)w * 32 + c4]);
    }
}

// ---------------- register-tiled SGEMM (static schedule) ----------------
template <bool RELU, int NMAT, bool NT>
__global__ __launch_bounds__(256) void k_gemm(
    const float* __restrict__ A0, const float* __restrict__ A1,
    const float* __restrict__ W0, const float* __restrict__ W1,
    const float* __restrict__ bias,
    float* __restrict__ out, int N)
{
    __shared__ float sA[128 * 36];
    __shared__ float sW[32 * 132];

    const int tid = threadIdx.x;
    const int tx  = tid & 15;
    const int ty  = tid >> 4;
    const int base = blockIdx.x * 128;

    float acc[2][2][4][4];
    #pragma unroll
    for (int a = 0; a < 2; ++a)
        #pragma unroll
        for (int b = 0; b < 2; ++b)
            #pragma unroll
            for (int i = 0; i < 4; ++i)
                #pragma unroll
                for (int j = 0; j < 4; ++j)
                    acc[a][b][i][j] = 0.0f;

    const int NCH = NMAT * 4;
    for (int c_i = 0; c_i < NCH; ++c_i) {
        const float* Asrc = (NMAT == 2 && c_i >= 4) ? A1 : A0;
        const float* Wsrc = (NMAT == 2 && c_i >= 4) ? W1 : W0;
        const int kc = (c_i & 3) * 32;

        __syncthreads();

        #pragma unroll
        for (int it = 0; it < 4; ++it) {
            int idx = it * 256 + tid;
            int row = idx >> 3, kq = idx & 7;
            int grow = base + row;
            if (grow >= N) grow = N - 1;
            float4 v = *reinterpret_cast<const float4*>(
                &Asrc[(size_t)grow * D + kc + kq * 4]);
            *reinterpret_cast<float4*>(&sA[row * 36 + kq * 4]) = v;
        }
        #pragma unroll
        for (int it = 0; it < 4; ++it) {
            int idx = it * 256 + tid;
            int j = idx >> 3, kq = idx & 7;
            float4 v = *reinterpret_cast<const float4*>(&Wsrc[j * D + kc + kq * 4]);
            sW[(kq * 4 + 0) * 132 + j] = v.x;
            sW[(kq * 4 + 1) * 132 + j] = v.y;
            sW[(kq * 4 + 2) * 132 + j] = v.z;
            sW[(kq * 4 + 3) * 132 + j] = v.w;
        }
        __syncthreads();

        #pragma unroll
        for (int kk = 0; kk < 32; kk += 4) {
            float4 av[2][4];
            #pragma unroll
            for (int rh = 0; rh < 2; ++rh)
                #pragma unroll
                for (int ri = 0; ri < 4; ++ri)
                    av[rh][ri] = *reinterpret_cast<const float4*>(
                        &sA[(rh * 64 + ty * 4 + ri) * 36 + kk]);
            float4 wv[4][2];
            #pragma unroll
            for (int kq = 0; kq < 4; ++kq)
                #pragma unroll
                for (int c = 0; c < 2; ++c)
                    wv[kq][c] = *reinterpret_cast<const float4*>(
                        &sW[(kk + kq) * 132 + c * 64 + tx * 4]);
            #pragma unroll
            for (int kq = 0; kq < 4; ++kq) {
                #pragma unroll
                for (int rh = 0; rh < 2; ++rh) {
                    #pragma unroll
                    for (int ri = 0; ri < 4; ++ri) {
                        float a = reinterpret_cast<const float*>(&av[rh][ri])[kq];
                        #pragma unroll
                        for (int c = 0; c < 2; ++c) {
                            float4 w = wv[kq][c];
                            acc[rh][c][ri][0] = fmaf(a, w.x, acc[rh][c][ri][0]);
                            acc[rh][c][ri][1] = fmaf(a, w.y, acc[rh][c][ri][1]);
                            acc[rh][c][ri][2] = fmaf(a, w.z, acc[rh][c][ri][2]);
                            acc[rh][c][ri][3] = fmaf(a, w.w, acc[rh][c][ri][3]);
                        }
                    }
                }
            }
        }
    }

    float4 b4[2];
    b4[0] = *reinterpret_cast<const float4*>(&bias[tx * 4]);
    b4[1] = *reinterpret_cast<const float4*>(&bias[64 + tx * 4]);
    #pragma unroll
    for (int rh = 0; rh < 2; ++rh) {
        #pragma unroll
        for (int ri = 0; ri < 4; ++ri) {
            int row = base + rh * 64 + ty * 4 + ri;
            if (row < N) {
                #pragma unroll
                for (int c = 0; c < 2; ++c) {
                    float4 o;
                    o.x = acc[rh][c][ri][0] + b4[c].x;
                    o.y = acc[rh][c][ri][1] + b4[c].y;
                    o.z = acc[rh][c][ri][2] + b4[c].z;
                    o.w = acc[rh][c][ri][3] + b4[c].w;
                    if (RELU) {
                        o.x = fmaxf(o.x, 0.0f); o.y = fmaxf(o.y, 0.0f);
                        o.z = fmaxf(o.z, 0.0f); o.w = fmaxf(o.w, 0.0f);
                    }
                    float4* dst = reinterpret_cast<float4*>(
                        &out[(size_t)row * D + c * 64 + tx * 4]);
                    if (NT) nt_store_f4(o, dst);
                    else    *dst = o;
                }
            }
        }
    }
}

// ---------------- fused dual-head GEMM ----------------
__global__ __launch_bounds__(512) void k_head2(
    const float* __restrict__ h,
    const float* __restrict__ Wv, const float* __restrict__ bv,
    const float* __restrict__ Wt, const float* __restrict__ bt,
    float* __restrict__ xv, float* __restrict__ xt, int N)
{
    __shared__ float sA [128 * 36];
    __shared__ float sWv[32 * 132];
    __shared__ float sWt[32 * 132];

    const int tid = threadIdx.x;
    const int tx  = tid & 31;
    const int ty  = tid >> 5;
    const int base = blockIdx.x * 128;

    float acc[2][2][4][4];
    #pragma unroll
    for (int a = 0; a < 2; ++a)
        #pragma unroll
        for (int b = 0; b < 2; ++b)
            #pragma unroll
            for (int i = 0; i < 4; ++i)
                #pragma unroll
                for (int j = 0; j < 4; ++j)
                    acc[a][b][i][j] = 0.0f;

    for (int c_i = 0; c_i < 4; ++c_i) {
        const int kc = c_i * 32;
        __syncthreads();

        #pragma unroll
        for (int it = 0; it < 2; ++it) {
            int idx = it * 512 + tid;
            int row = idx >> 3, kq = idx & 7;
            int grow = base + row;
            if (grow >= N) grow = N - 1;
            float4 v = *reinterpret_cast<const float4*>(
                &h[(size_t)grow * D + kc + kq * 4]);
            *reinterpret_cast<float4*>(&sA[row * 36 + kq * 4]) = v;
        }
        #pragma unroll
        for (int it = 0; it < 2; ++it) {
            int idx = it * 512 + tid;
            int j = idx >> 3, kq = idx & 7;
            float4 v = *reinterpret_cast<const float4*>(&Wv[j * D + kc + kq * 4]);
            sWv[(kq * 4 + 0) * 132 + j] = v.x;
            sWv[(kq * 4 + 1) * 132 + j] = v.y;
            sWv[(kq * 4 + 2) * 132 + j] = v.z;
            sWv[(kq * 4 + 3) * 132 + j] = v.w;
            float4 u = *reinterpret_cast<const float4*>(&Wt[j * D + kc + kq * 4]);
            sWt[(kq * 4 + 0) * 132 + j] = u.x;
            sWt[(kq * 4 + 1) * 132 + j] = u.y;
            sWt[(kq * 4 + 2) * 132 + j] = u.z;
            sWt[(kq * 4 + 3) * 132 + j] = u.w;
        }
        __syncthreads();

        #pragma unroll
        for (int kk = 0; kk < 32; kk += 4) {
            float4 av[2][4];
            #pragma unroll
            for (int rh = 0; rh < 2; ++rh)
                #pragma unroll
                for (int ri = 0; ri < 4; ++ri)
                    av[rh][ri] = *reinterpret_cast<const float4*>(
                        &sA[(rh * 64 + ty * 4 + ri) * 36 + kk]);
            float4 wv[4][2];
            #pragma unroll
            for (int kq = 0; kq < 4; ++kq) {
                wv[kq][0] = *reinterpret_cast<const float4*>(
                    &sWv[(kk + kq) * 132 + tx * 4]);
                wv[kq][1] = *reinterpret_cast<const float4*>(
                    &sWt[(kk + kq) * 132 + tx * 4]);
            }
            #pragma unroll
            for (int kq = 0; kq < 4; ++kq) {
                #pragma unroll
                for (int rh = 0; rh < 2; ++rh) {
                    #pragma unroll
                    for (int ri = 0; ri < 4; ++ri) {
                        float a = reinterpret_cast<const float*>(&av[rh][ri])[kq];
                        #pragma unroll
                        for (int c = 0; c < 2; ++c) {
                            float4 w = wv[kq][c];
                            acc[rh][c][ri][0] = fmaf(a, w.x, acc[rh][c][ri][0]);
                            acc[rh][c][ri][1] = fmaf(a, w.y, acc[rh][c][ri][1]);
                            acc[rh][c][ri][2] = fmaf(a, w.z, acc[rh][c][ri][2]);
                            acc[rh][c][ri][3] = fmaf(a, w.w, acc[rh][c][ri][3]);
                        }
                    }
                }
            }
        }
    }

    float4 bv4 = *reinterpret_cast<const float4*>(&bv[tx * 4]);
    float4 bt4 = *reinterpret_cast<const float4*>(&bt[tx * 4]);
    #pragma unroll
    for (int rh = 0; rh < 2; ++rh) {
        #pragma unroll
        for (int ri = 0; ri < 4; ++ri) {
            int row = base + rh * 64 + ty * 4 + ri;
            if (row < N) {
                float4 o;
                o.x = fmaxf(acc[rh][0][ri][0] + bv4.x, 0.0f);
                o.y = fmaxf(acc[rh][0][ri][1] + bv4.y, 0.0f);
                o.z = fmaxf(acc[rh][0][ri][2] + bv4.z, 0.0f);
                o.w = fmaxf(acc[rh][0][ri][3] + bv4.w, 0.0f);
                nt_store_f4(o, reinterpret_cast<float4*>(&xv[(size_t)row * D + tx * 4]));
                float4 q;
                q.x = fmaxf(acc[rh][1][ri][0] + bt4.x, 0.0f);
                q.y = fmaxf(acc[rh][1][ri][1] + bt4.y, 0.0f);
                q.z = fmaxf(acc[rh][1][ri][2] + bt4.z, 0.0f);
                q.w = fmaxf(acc[rh][1][ri][3] + bt4.w, 0.0f);
                nt_store_f4(q, reinterpret_cast<float4*>(&xt[(size_t)row * D + tx * 4]));
            }
        }
    }
}

extern "C" void kernel_launch(void* const* d_in, const int* in_sizes, int n_in,
                              void* d_out, int out_size, void* d_ws, size_t ws_size,
                              hipStream_t stream) {
    const float* x   = (const float*)d_in[0];
    const int*   ei  = (const int*)d_in[1];
    const float* Wl0 = (const float*)d_in[2];
    const float* bl0 = (const float*)d_in[3];
    const float* Wr0 = (const float*)d_in[4];
    const float* Wl1 = (const float*)d_in[5];
    const float* bl1 = (const float*)d_in[6];
    const float* Wr1 = (const float*)d_in[7];
    const float* Wv  = (const float*)d_in[8];
    const float* bv  = (const float*)d_in[9];
    const float* Wt  = (const float*)d_in[10];
    const float* bt  = (const float*)d_in[11];

    const int N = in_sizes[0] / D;       // 100000
    const int E = in_sizes[1] / 2;       // 1600000
    const int* srcv = ei;
    const int* dstv = ei + E;

    float* out  = (float*)d_out;
    const size_t nd = (size_t)N * D;
    float* h    = out;                        // final output 0
    float* h1   = out + nd;                   // scratch, later x_vision
    float* aggb = out + 2 * nd;               // scratch, later x_text

    const int nb   = (N + 4095) / 4096;
    const int nseg = (N + (1 << SEG_SHIFT) - 1) >> SEG_SHIFT;

    // int workspace: deg(N) | rowptr(N+1) | cursor(N) | csr(E) | bsum(nb)
    size_t intWords  = (size_t)(3 * N + 1) + (size_t)E + (size_t)nb;
    size_t need_ints = intWords * sizeof(int);
    size_t ints_pad  = (need_ints + 15) & ~(size_t)15;
    size_t need_all  = ints_pad + nd * sizeof(__half);

    int* wsI;
    __half* xh;
    if (ws_size >= need_all) {
        wsI = (int*)d_ws;
        xh  = (__half*)((char*)d_ws + ints_pad);
    } else if (ws_size >= need_ints) {
        wsI = (int*)d_ws;
        xh  = (__half*)h;                     // h free until layer-1 gemm
    } else {
        wsI = (int*)h;
        xh  = (__half*)((char*)h + ints_pad); // ints 7.6MB + fp16 25.6MB < 51.2MB
    }
    int* degI   = wsI;
    int* rowptr = wsI + N;
    int* cursor = wsI + 2 * N + 1;
    int* csr    = wsI + 3 * N + 1;
    int* bsum   = wsI + 3 * N + 1 + E;

    (void)hipMemsetAsync(degI, 0, (size_t)N * sizeof(int), stream);
    k_deg <<<2048, 256, 0, stream>>>(dstv, degI, E, nseg);
    k_scan_a<<<nb, 1024, 0, stream>>>(degI, rowptr, bsum, N);
    k_scan_b<<<nb, 1024, 0, stream>>>(rowptr, cursor, bsum, N, nb);
    k_fill<<<2048, 256, 0, stream>>>(srcv, dstv, cursor, csr, E, nseg);

    const int agg_blocks  = (int)(((size_t)N * 64 + 511) / 512);
    const int gemm_blocks = (N + 127) / 128;
    const int n8 = (int)(nd / 8);

    // ---- layer 0 ----
    k_cvt<<<2048, 256, 0, stream>>>(x, xh, n8);
    k_agg<<<agg_blocks, 512, 0, stream>>>(rowptr, csr, xh, aggb, N);
    k_gemm<true, 2, false><<<gemm_blocks, 256, 0, stream>>>(aggb, x, Wl0, Wr0, bl0, h1, N);

    // ---- layer 1 ----
    k_cvt<<<2048, 256, 0, stream>>>(h1, xh, n8);
    k_agg<<<agg_blocks, 512, 0, stream>>>(rowptr, csr, xh, aggb, N);
    k_gemm<false, 2, false><<<gemm_blocks, 256, 0, stream>>>(aggb, h1, Wl1, Wr1, bl1, h, N);

    // ---- fused heads ----
    k_head2<<<gemm_blocks, 512, 0, stream>>>(h, Wv, bv, Wt, bt,
                                             out + nd, out + 2 * nd, N);
}

// Round 9
// 567.567 us; speedup vs baseline: 3.2182x; 1.1814x over previous
//
#include <hip/hip_runtime.h>
#include <hip/hip_fp16.h>

#define D 128
#define SEG_SHIFT 15              // 32768-node atomic window; 4 passes over edges

typedef _Float16 f16x8 __attribute__((ext_vector_type(8)));
typedef float    f32x4 __attribute__((ext_vector_type(4)));
typedef int      nint2 __attribute__((ext_vector_type(2)));

// ---------------- fp32 -> fp16 cast (vectorized) ----------------
__global__ __launch_bounds__(256) void k_cvt(const float* __restrict__ in,
                                             __half* __restrict__ out, int n8) {
    int i = blockIdx.x * 256 + threadIdx.x;
    const int stride = gridDim.x * 256;
    for (; i < n8; i += stride) {
        float4 a = reinterpret_cast<const float4*>(in)[(size_t)i * 2];
        float4 b = reinterpret_cast<const float4*>(in)[(size_t)i * 2 + 1];
        __half2 h0 = __floats2half2_rn(a.x, a.y);
        __half2 h1 = __floats2half2_rn(a.z, a.w);
        __half2 h2 = __floats2half2_rn(b.x, b.y);
        __half2 h3 = __floats2half2_rn(b.z, b.w);
        int4 o;
        o.x = *reinterpret_cast<int*>(&h0);
        o.y = *reinterpret_cast<int*>(&h1);
        o.z = *reinterpret_cast<int*>(&h2);
        o.w = *reinterpret_cast<int*>(&h3);
        reinterpret_cast<int4*>(out)[i] = o;
    }
}

// ---------------- 4 weight matrices fp32 -> fp16 ----------------
__global__ __launch_bounds__(256) void k_cvtw(const float* __restrict__ W0,
                                              const float* __restrict__ W1,
                                              const float* __restrict__ W2,
                                              const float* __restrict__ W3,
                                              _Float16* __restrict__ out) {
    int idx = blockIdx.x * 256 + threadIdx.x;      // 8192 chunks of 8 elems
    if (idx >= 8192) return;
    int mat = idx >> 11;                            // 2048 chunks per matrix
    int off = idx & 2047;
    const float* s = (mat == 0) ? W0 : (mat == 1) ? W1 : (mat == 2) ? W2 : W3;
    float4 a = reinterpret_cast<const float4*>(s)[(size_t)off * 2];
    float4 b = reinterpret_cast<const float4*>(s)[(size_t)off * 2 + 1];
    __half2 h0 = __floats2half2_rn(a.x, a.y);
    __half2 h1 = __floats2half2_rn(a.z, a.w);
    __half2 h2 = __floats2half2_rn(b.x, b.y);
    __half2 h3 = __floats2half2_rn(b.z, b.w);
    int4 o;
    o.x = *reinterpret_cast<int*>(&h0);
    o.y = *reinterpret_cast<int*>(&h1);
    o.z = *reinterpret_cast<int*>(&h2);
    o.w = *reinterpret_cast<int*>(&h3);
    reinterpret_cast<int4*>(out)[idx] = o;
}

// ---------------- segmented degree histogram ----------------
__global__ __launch_bounds__(256) void k_deg(const int* __restrict__ dst,
                                             int* __restrict__ deg, int E, int nseg) {
    const int stride = gridDim.x * blockDim.x;
    const int t0 = blockIdx.x * blockDim.x + threadIdx.x;
    for (int seg = 0; seg < nseg; ++seg) {
        const int lo = seg << SEG_SHIFT, hi = lo + (1 << SEG_SHIFT);
        for (int e = t0; e < E; e += stride) {
            int d = __builtin_nontemporal_load(&dst[e]);
            if (d >= lo && d < hi) atomicAdd(&deg[d], 1);
        }
    }
}

// ---------------- multi-block exclusive scan, phase A ----------------
__global__ __launch_bounds__(1024) void k_scan_a(const int* __restrict__ deg,
                                                 int* __restrict__ rowptr,
                                                 int* __restrict__ bsum, int N) {
    __shared__ int wsum[16];
    __shared__ int wscan[16];
    const int tid = threadIdx.x, lane = tid & 63, wid = tid >> 6;
    const int i = blockIdx.x * 4096 + tid * 4;
    int4 v = *reinterpret_cast<const int4*>(&deg[i]);
    int v0 = (i     < N) ? v.x : 0;
    int v1 = (i + 1 < N) ? v.y : 0;
    int v2 = (i + 2 < N) ? v.z : 0;
    int v3 = (i + 3 < N) ? v.w : 0;
    const int t = v0 + v1 + v2 + v3;
    int x = t;
    #pragma unroll
    for (int off = 1; off < 64; off <<= 1) {
        int u = __shfl_up(x, off);
        if (lane >= off) x += u;
    }
    if (lane == 63) wsum[wid] = x;
    __syncthreads();
    if (wid == 0) {
        int s = (lane < 16) ? wsum[lane] : 0;
        #pragma unroll
        for (int off = 1; off < 16; off <<= 1) {
            int u = __shfl_up(s, off);
            if (lane >= off) s += u;
        }
        if (lane < 16) wscan[lane] = s;
    }
    __syncthreads();
    int excl = x - t + ((wid > 0) ? wscan[wid - 1] : 0);
    if (i     < N) rowptr[i]     = excl;
    if (i + 1 < N) rowptr[i + 1] = excl + v0;
    if (i + 2 < N) rowptr[i + 2] = excl + v0 + v1;
    if (i + 3 < N) rowptr[i + 3] = excl + v0 + v1 + v2;
    if (tid == 0) bsum[blockIdx.x] = wscan[15];
}

// ---------------- scan phase B: add block offsets, seed cursor ----------------
__global__ __launch_bounds__(1024) void k_scan_b(int* __restrict__ rowptr,
                                                 int* __restrict__ cursor,
                                                 const int* __restrict__ bsum,
                                                 int N, int nb) {
    __shared__ int s_off;
    if (threadIdx.x == 0) {
        int o = 0;
        for (int b = 0; b < (int)blockIdx.x; ++b) o += bsum[b];
        s_off = o;
        if ((int)blockIdx.x == nb - 1) rowptr[N] = o + bsum[nb - 1];
    }
    __syncthreads();
    const int off = s_off;
    const int i = blockIdx.x * 4096 + threadIdx.x * 4;
    if (i + 3 < N) {
        int4 r = *reinterpret_cast<const int4*>(&rowptr[i]);
        r.x += off; r.y += off; r.z += off; r.w += off;
        *reinterpret_cast<int4*>(&rowptr[i]) = r;
        *reinterpret_cast<int4*>(&cursor[i]) = r;
    } else {
        #pragma unroll
        for (int k = 0; k < 4; ++k) {
            int ii = i + k;
            if (ii < N) {
                int r = rowptr[ii] + off;
                rowptr[ii] = r;
                cursor[ii] = r;
            }
        }
    }
}

// ---------------- segmented CSR fill ----------------
__global__ __launch_bounds__(256) void k_fill(const int* __restrict__ src,
                                              const int* __restrict__ dst,
                                              int* __restrict__ cursor,
                                              int* __restrict__ csr, int E, int nseg) {
    const int stride = gridDim.x * blockDim.x;
    const int t0 = blockIdx.x * blockDim.x + threadIdx.x;
    for (int seg = 0; seg < nseg; ++seg) {
        const int lo = seg << SEG_SHIFT, hi = lo + (1 << SEG_SHIFT);
        for (int e = t0; e < E; e += stride) {
            int d = __builtin_nontemporal_load(&dst[e]);
            if (d >= lo && d < hi) {
                int p = atomicAdd(&cursor[d], 1);
                csr[p] = __builtin_nontemporal_load(&src[e]);
            }
        }
    }
}

// ---------------- gather-mean aggregation (fp16 in, fp32 accum, fp16 out) ----------------
__device__ __forceinline__ void acc_add(float4& a, int2 raw) {
    __half2 h01 = *reinterpret_cast<const __half2*>(&raw.x);
    __half2 h23 = *reinterpret_cast<const __half2*>(&raw.y);
    float2 f01 = __half22float2(h01);
    float2 f23 = __half22float2(h23);
    a.x += f01.x; a.y += f01.y; a.z += f23.x; a.w += f23.y;
}

__global__ __launch_bounds__(512) void k_agg(const int* __restrict__ rowptr,
                                             const int* __restrict__ csr,
                                             const __half* __restrict__ xh,
                                             __half* __restrict__ agg, int N) {
    int w = (int)((blockIdx.x * 512u + threadIdx.x) >> 6);
    int lane = threadIdx.x & 63;
    if (w >= N) return;
    int s0 = rowptr[w], s1 = rowptr[w + 1];
    const int half = lane >> 5;
    const int c4 = lane & 31;                 // 8B chunk index within row
    const int2* xh2 = reinterpret_cast<const int2*>(xh);
    float4 a0 = make_float4(0.f, 0.f, 0.f, 0.f);
    float4 a1 = make_float4(0.f, 0.f, 0.f, 0.f);
    float4 a2 = make_float4(0.f, 0.f, 0.f, 0.f);
    float4 a3 = make_float4(0.f, 0.f, 0.f, 0.f);

    for (int p = s0; p < s1; p += 64) {
        int m = s1 - p; if (m > 64) m = 64;
        int my = (p + lane < s1) ? csr[p + lane] : 0;
        int j = 0;
        for (; j + 15 < m; j += 16) {
            int r0 = __shfl(my, j +      half);
            int r1 = __shfl(my, j + 2  + half);
            int r2 = __shfl(my, j + 4  + half);
            int r3 = __shfl(my, j + 6  + half);
            int r4 = __shfl(my, j + 8  + half);
            int r5 = __shfl(my, j + 10 + half);
            int r6 = __shfl(my, j + 12 + half);
            int r7 = __shfl(my, j + 14 + half);
            int2 v0 = xh2[(size_t)r0 * 32 + c4];
            int2 v1 = xh2[(size_t)r1 * 32 + c4];
            int2 v2 = xh2[(size_t)r2 * 32 + c4];
            int2 v3 = xh2[(size_t)r3 * 32 + c4];
            int2 v4 = xh2[(size_t)r4 * 32 + c4];
            int2 v5 = xh2[(size_t)r5 * 32 + c4];
            int2 v6 = xh2[(size_t)r6 * 32 + c4];
            int2 v7 = xh2[(size_t)r7 * 32 + c4];
            acc_add(a0, v0); acc_add(a1, v1); acc_add(a2, v2); acc_add(a3, v3);
            acc_add(a0, v4); acc_add(a1, v5); acc_add(a2, v6); acc_add(a3, v7);
        }
        for (; j + 7 < m; j += 8) {
            int r0 = __shfl(my, j +     half);
            int r1 = __shfl(my, j + 2 + half);
            int r2 = __shfl(my, j + 4 + half);
            int r3 = __shfl(my, j + 6 + half);
            int2 v0 = xh2[(size_t)r0 * 32 + c4];
            int2 v1 = xh2[(size_t)r1 * 32 + c4];
            int2 v2 = xh2[(size_t)r2 * 32 + c4];
            int2 v3 = xh2[(size_t)r3 * 32 + c4];
            acc_add(a0, v0); acc_add(a1, v1); acc_add(a2, v2); acc_add(a3, v3);
        }
        for (; j + 1 < m; j += 2) {
            int r0 = __shfl(my, j + half);
            int2 v0 = xh2[(size_t)r0 * 32 + c4];
            acc_add(a0, v0);
        }
        if (j < m) {
            int r0 = __shfl(my, j);
            int2 v0 = xh2[(size_t)r0 * 32 + c4];
            if (half == 0) acc_add(a0, v0);
        }
    }

    float4 s;
    s.x = (a0.x + a1.x) + (a2.x + a3.x);
    s.y = (a0.y + a1.y) + (a2.y + a3.y);
    s.z = (a0.z + a1.z) + (a2.z + a3.z);
    s.w = (a0.w + a1.w) + (a2.w + a3.w);
    s.x += __shfl_xor(s.x, 32);
    s.y += __shfl_xor(s.y, 32);
    s.z += __shfl_xor(s.z, 32);
    s.w += __shfl_xor(s.w, 32);

    float inv = 1.0f / fmaxf((float)(s1 - s0), 1.0f);
    if (half == 0) {
        __half2 p01 = __floats2half2_rn(s.x * inv, s.y * inv);
        __half2 p23 = __floats2half2_rn(s.z * inv, s.w * inv);
        nint2 o;
        o.x = *reinterpret_cast<int*>(&p01);
        o.y = *reinterpret_cast<int*>(&p23);
        __builtin_nontemporal_store(o, reinterpret_cast<nint2*>(agg) + (size_t)w * 32 + c4);
    }
}

// ---------------- MFMA fused-layer GEMM ----------------
// out = act( A0@W0^T + A1@W1^T + bias ),  A fp16 [N][128], W fp16 [128][128].
// 256 thr = 4 waves; block tile 64 rows x 128 cols; wave tile 16 x 128.
// Fragments straight from global (W is L2-resident); no LDS.
// Layouts (gfx950 16x16x32): A: row=lane&15, k=(lane>>4)*8+j; B(=W rows as cols):
// col=lane&15, k likewise; D: col=lane&15, row=(lane>>4)*4+reg.
template <bool RELU, bool OUT_HALF>
__global__ __launch_bounds__(256) void k_mfma2(
    const _Float16* __restrict__ A0, const _Float16* __restrict__ A1,
    const _Float16* __restrict__ W0h, const _Float16* __restrict__ W1h,
    const float* __restrict__ bias,
    float* __restrict__ outF, _Float16* __restrict__ outH, int N)
{
    const int wv = threadIdx.x >> 6;
    const int l  = threadIdx.x & 63;
    const int lr = l & 15;
    const int lk = (l >> 4) * 8;
    const int m0 = blockIdx.x * 64 + wv * 16;

    int arow = m0 + lr; if (arow >= N) arow = N - 1;

    f32x4 zero = {0.f, 0.f, 0.f, 0.f};
    f32x4 acc[8];
    #pragma unroll
    for (int g = 0; g < 8; ++g) acc[g] = zero;

    #pragma unroll
    for (int mat = 0; mat < 2; ++mat) {
        const _Float16* Ap = (mat ? A1 : A0) + (size_t)arow * D + lk;
        const _Float16* Wp = (mat ? W1h : W0h) + (size_t)lr * D + lk;
        #pragma unroll
        for (int kc = 0; kc < D; kc += 32) {
            f16x8 a = *reinterpret_cast<const f16x8*>(Ap + kc);
            #pragma unroll
            for (int g = 0; g < 8; ++g) {
                f16x8 b = *reinterpret_cast<const f16x8*>(Wp + g * 16 * D + kc);
                acc[g] = __builtin_amdgcn_mfma_f32_16x16x32_f16(a, b, acc[g], 0, 0, 0);
            }
        }
    }

    float bia[8];
    #pragma unroll
    for (int g = 0; g < 8; ++g) bia[g] = bias[g * 16 + lr];

    const int rbase = m0 + (l >> 4) * 4;
    #pragma unroll
    for (int r = 0; r < 4; ++r) {
        int row = rbase + r;
        if (row < N) {
            #pragma unroll
            for (int g = 0; g < 8; ++g) {
                float v = acc[g][r] + bia[g];
                if (RELU) v = fmaxf(v, 0.0f);
                int col = g * 16 + lr;
                if (OUT_HALF) outH[(size_t)row * D + col] = (_Float16)v;
                else __builtin_nontemporal_store(v, &outF[(size_t)row * D + col]);
            }
        }
    }
}

// ---------------- MFMA dual-head GEMM (fp32 in, in-register fp16 cvt) ----------------
__global__ __launch_bounds__(256) void k_headm(
    const float* __restrict__ h,
    const float* __restrict__ Wv, const float* __restrict__ bv,
    const float* __restrict__ Wt, const float* __restrict__ bt,
    float* __restrict__ xv, float* __restrict__ xt, int N)
{
    const int wv_ = threadIdx.x >> 6;
    const int l  = threadIdx.x & 63;
    const int lr = l & 15;
    const int lk = (l >> 4) * 8;
    const int m0 = blockIdx.x * 64 + wv_ * 16;

    int arow = m0 + lr; if (arow >= N) arow = N - 1;

    f32x4 zero = {0.f, 0.f, 0.f, 0.f};
    f32x4 accv[8], acct[8];
    #pragma unroll
    for (int g = 0; g < 8; ++g) { accv[g] = zero; acct[g] = zero; }

    const float* Ap = h + (size_t)arow * D + lk;
    #pragma unroll
    for (int kc = 0; kc < D; kc += 32) {
        float4 a0 = *reinterpret_cast<const float4*>(Ap + kc);
        float4 a1 = *reinterpret_cast<const float4*>(Ap + kc + 4);
        f16x8 a;
        a[0] = (_Float16)a0.x; a[1] = (_Float16)a0.y;
        a[2] = (_Float16)a0.z; a[3] = (_Float16)a0.w;
        a[4] = (_Float16)a1.x; a[5] = (_Float16)a1.y;
        a[6] = (_Float16)a1.z; a[7] = (_Float16)a1.w;
        #pragma unroll
        for (int g = 0; g < 8; ++g) {
            const float* wvp = Wv + (size_t)(g * 16 + lr) * D + kc + lk;
            float4 w0 = *reinterpret_cast<const float4*>(wvp);
            float4 w1 = *reinterpret_cast<const float4*>(wvp + 4);
            f16x8 b;
            b[0] = (_Float16)w0.x; b[1] = (_Float16)w0.y;
            b[2] = (_Float16)w0.z; b[3] = (_Float16)w0.w;
            b[4] = (_Float16)w1.x; b[5] = (_Float16)w1.y;
            b[6] = (_Float16)w1.z; b[7] = (_Float16)w1.w;
            accv[g] = __builtin_amdgcn_mfma_f32_16x16x32_f16(a, b, accv[g], 0, 0, 0);
            const float* wtp = Wt + (size_t)(g * 16 + lr) * D + kc + lk;
            float4 t0 = *reinterpret_cast<const float4*>(wtp);
            float4 t1 = *reinterpret_cast<const float4*>(wtp + 4);
            f16x8 c;
            c[0] = (_Float16)t0.x; c[1] = (_Float16)t0.y;
            c[2] = (_Float16)t0.z; c[3] = (_Float16)t0.w;
            c[4] = (_Float16)t1.x; c[5] = (_Float16)t1.y;
            c[6] = (_Float16)t1.z; c[7] = (_Float16)t1.w;
            acct[g] = __builtin_amdgcn_mfma_f32_16x16x32_f16(a, c, acct[g], 0, 0, 0);
        }
    }

    float bvv[8], btt[8];
    #pragma unroll
    for (int g = 0; g < 8; ++g) {
        bvv[g] = bv[g * 16 + lr];
        btt[g] = bt[g * 16 + lr];
    }

    const int rbase = m0 + (l >> 4) * 4;
    #pragma unroll
    for (int r = 0; r < 4; ++r) {
        int row = rbase + r;
        if (row < N) {
            #pragma unroll
            for (int g = 0; g < 8; ++g) {
                int col = g * 16 + lr;
                float v = fmaxf(accv[g][r] + bvv[g], 0.0f);
                float t = fmaxf(acct[g][r] + btt[g], 0.0f);
                __builtin_nontemporal_store(v, &xv[(size_t)row * D + col]);
                __builtin_nontemporal_store(t, &xt[(size_t)row * D + col]);
            }
        }
    }
}

extern "C" void kernel_launch(void* const* d_in, const int* in_sizes, int n_in,
                              void* d_out, int out_size, void* d_ws, size_t ws_size,
                              hipStream_t stream) {
    const float* x   = (const float*)d_in[0];
    const int*   ei  = (const int*)d_in[1];
    const float* Wl0 = (const float*)d_in[2];
    const float* bl0 = (const float*)d_in[3];
    const float* Wr0 = (const float*)d_in[4];
    const float* Wl1 = (const float*)d_in[5];
    const float* bl1 = (const float*)d_in[6];
    const float* Wr1 = (const float*)d_in[7];
    const float* Wv  = (const float*)d_in[8];
    const float* bv  = (const float*)d_in[9];
    const float* Wt  = (const float*)d_in[10];
    const float* bt  = (const float*)d_in[11];

    const int N = in_sizes[0] / D;       // 100000
    const int E = in_sizes[1] / 2;       // 1600000
    const int* srcv = ei;
    const int* dstv = ei + E;

    float* out = (float*)d_out;
    const size_t nd = (size_t)N * D;
    float* h   = out;                    // final output 0
    float* xvp = out + nd;               // final output 1 (x_vision)
    float* xtp = out + 2 * nd;           // final output 2 (x_text)

    // Scratch placement with verified lifetimes (all inside out; no d_ws needed):
    //  h  region: xh (fp16, 25.6MB)          — dead before gemm1 writes h
    //  xv region: h1h (25.6MB) + Wh4 (128KB) — dead before k_headm writes xv
    //  xt region: ints (7.6MB) + aggh (25.6) — dead before k_headm writes xt
    __half*    xh   = (__half*)h;
    __half*    h1h  = (__half*)xvp;
    _Float16*  Wh4  = (_Float16*)((char*)xvp + nd * sizeof(__half));
    _Float16*  Wl0h = Wh4;
    _Float16*  Wr0h = Wh4 + 16384;
    _Float16*  Wl1h = Wh4 + 32768;
    _Float16*  Wr1h = Wh4 + 49152;

    const int nb   = (N + 4095) / 4096;
    const int nseg = (N + (1 << SEG_SHIFT) - 1) >> SEG_SHIFT;
    size_t intWords = (size_t)(3 * N + 1) + (size_t)E + (size_t)nb;
    size_t ints_pad = (intWords * sizeof(int) + 15) & ~(size_t)15;

    int* wsI    = (int*)xtp;
    int* degI   = wsI;
    int* rowptr = wsI + N;
    int* cursor = wsI + 2 * N + 1;
    int* csr    = wsI + 3 * N + 1;
    int* bsum   = wsI + 3 * N + 1 + E;
    __half* aggh = (__half*)((char*)xtp + ints_pad);

    // ---- CSR build ----
    (void)hipMemsetAsync(degI, 0, (size_t)N * sizeof(int), stream);
    k_deg <<<2048, 256, 0, stream>>>(dstv, degI, E, nseg);
    k_scan_a<<<nb, 1024, 0, stream>>>(degI, rowptr, bsum, N);
    k_scan_b<<<nb, 1024, 0, stream>>>(rowptr, cursor, bsum, N, nb);
    k_fill<<<2048, 256, 0, stream>>>(srcv, dstv, cursor, csr, E, nseg);

    const int agg_blocks = (int)(((size_t)N * 64 + 511) / 512);
    const int mblocks    = (N + 63) / 64;
    const int n8         = (int)(nd / 8);

    // ---- conversions ----
    k_cvt <<<2048, 256, 0, stream>>>(x, xh, n8);
    k_cvtw<<<32, 256, 0, stream>>>(Wl0, Wr0, Wl1, Wr1, Wh4);

    // ---- layer 0: h1 = relu(agg(x)@Wl0^T + bl0 + x@Wr0^T), emitted fp16 ----
    k_agg<<<agg_blocks, 512, 0, stream>>>(rowptr, csr, xh, aggh, N);
    k_mfma2<true, true><<<mblocks, 256, 0, stream>>>(
        (const _Float16*)aggh, (const _Float16*)xh, Wl0h, Wr0h, bl0,
        nullptr, (_Float16*)h1h, N);

    // ---- layer 1: h = agg(h1)@Wl1^T + bl1 + h1@Wr1^T (fp32 final) ----
    k_agg<<<agg_blocks, 512, 0, stream>>>(rowptr, csr, h1h, aggh, N);
    k_mfma2<false, false><<<mblocks, 256, 0, stream>>>(
        (const _Float16*)aggh, (const _Float16*)h1h, Wl1h, Wr1h, bl1,
        h, nullptr, N);

    // ---- heads: xv = relu(h@Wv^T+bv), xt = relu(h@Wt^T+bt) ----
    k_headm<<<mblocks, 256, 0, stream>>>(h, Wv, bv, Wt, bt, xvp, xtp, N);
}

// Round 10
// 478.472 us; speedup vs baseline: 3.8174x; 1.1862x over previous
//
#include <hip/hip_runtime.h>
#include <hip/hip_fp16.h>

#define D 128
#define SEG_SHIFT 15              // 32768-node atomic window; 4 passes over edges

typedef _Float16 f16x8 __attribute__((ext_vector_type(8)));
typedef float    f32x4 __attribute__((ext_vector_type(4)));
typedef int      nint2 __attribute__((ext_vector_type(2)));

// ---------------- fp32 -> fp16 cast (vectorized) ----------------
__global__ __launch_bounds__(256) void k_cvt(const float* __restrict__ in,
                                             __half* __restrict__ out, int n8) {
    int i = blockIdx.x * 256 + threadIdx.x;
    const int stride = gridDim.x * 256;
    for (; i < n8; i += stride) {
        float4 a = reinterpret_cast<const float4*>(in)[(size_t)i * 2];
        float4 b = reinterpret_cast<const float4*>(in)[(size_t)i * 2 + 1];
        __half2 h0 = __floats2half2_rn(a.x, a.y);
        __half2 h1 = __floats2half2_rn(a.z, a.w);
        __half2 h2 = __floats2half2_rn(b.x, b.y);
        __half2 h3 = __floats2half2_rn(b.z, b.w);
        int4 o;
        o.x = *reinterpret_cast<int*>(&h0);
        o.y = *reinterpret_cast<int*>(&h1);
        o.z = *reinterpret_cast<int*>(&h2);
        o.w = *reinterpret_cast<int*>(&h3);
        reinterpret_cast<int4*>(out)[i] = o;
    }
}

// ---------------- 4 weight matrices fp32 -> fp16 ----------------
__global__ __launch_bounds__(256) void k_cvtw(const float* __restrict__ W0,
                                              const float* __restrict__ W1,
                                              const float* __restrict__ W2,
                                              const float* __restrict__ W3,
                                              _Float16* __restrict__ out) {
    int idx = blockIdx.x * 256 + threadIdx.x;      // 8192 chunks of 8 elems
    if (idx >= 8192) return;
    int mat = idx >> 11;                            // 2048 chunks per matrix
    int off = idx & 2047;
    const float* s = (mat == 0) ? W0 : (mat == 1) ? W1 : (mat == 2) ? W2 : W3;
    float4 a = reinterpret_cast<const float4*>(s)[(size_t)off * 2];
    float4 b = reinterpret_cast<const float4*>(s)[(size_t)off * 2 + 1];
    __half2 h0 = __floats2half2_rn(a.x, a.y);
    __half2 h1 = __floats2half2_rn(a.z, a.w);
    __half2 h2 = __floats2half2_rn(b.x, b.y);
    __half2 h3 = __floats2half2_rn(b.z, b.w);
    int4 o;
    o.x = *reinterpret_cast<int*>(&h0);
    o.y = *reinterpret_cast<int*>(&h1);
    o.z = *reinterpret_cast<int*>(&h2);
    o.w = *reinterpret_cast<int*>(&h3);
    reinterpret_cast<int4*>(out)[idx] = o;
}

// ---------------- segmented degree histogram ----------------
__global__ __launch_bounds__(256) void k_deg(const int* __restrict__ dst,
                                             int* __restrict__ deg, int E, int nseg) {
    const int stride = gridDim.x * blockDim.x;
    const int t0 = blockIdx.x * blockDim.x + threadIdx.x;
    for (int seg = 0; seg < nseg; ++seg) {
        const int lo = seg << SEG_SHIFT, hi = lo + (1 << SEG_SHIFT);
        for (int e = t0; e < E; e += stride) {
            int d = __builtin_nontemporal_load(&dst[e]);
            if (d >= lo && d < hi) atomicAdd(&deg[d], 1);
        }
    }
}

// ---------------- multi-block exclusive scan, phase A ----------------
__global__ __launch_bounds__(1024) void k_scan_a(const int* __restrict__ deg,
                                                 int* __restrict__ rowptr,
                                                 int* __restrict__ bsum, int N) {
    __shared__ int wsum[16];
    __shared__ int wscan[16];
    const int tid = threadIdx.x, lane = tid & 63, wid = tid >> 6;
    const int i = blockIdx.x * 4096 + tid * 4;
    int4 v = *reinterpret_cast<const int4*>(&deg[i]);
    int v0 = (i     < N) ? v.x : 0;
    int v1 = (i + 1 < N) ? v.y : 0;
    int v2 = (i + 2 < N) ? v.z : 0;
    int v3 = (i + 3 < N) ? v.w : 0;
    const int t = v0 + v1 + v2 + v3;
    int x = t;
    #pragma unroll
    for (int off = 1; off < 64; off <<= 1) {
        int u = __shfl_up(x, off);
        if (lane >= off) x += u;
    }
    if (lane == 63) wsum[wid] = x;
    __syncthreads();
    if (wid == 0) {
        int s = (lane < 16) ? wsum[lane] : 0;
        #pragma unroll
        for (int off = 1; off < 16; off <<= 1) {
            int u = __shfl_up(s, off);
            if (lane >= off) s += u;
        }
        if (lane < 16) wscan[lane] = s;
    }
    __syncthreads();
    int excl = x - t + ((wid > 0) ? wscan[wid - 1] : 0);
    if (i     < N) rowptr[i]     = excl;
    if (i + 1 < N) rowptr[i + 1] = excl + v0;
    if (i + 2 < N) rowptr[i + 2] = excl + v0 + v1;
    if (i + 3 < N) rowptr[i + 3] = excl + v0 + v1 + v2;
    if (tid == 0) bsum[blockIdx.x] = wscan[15];
}

// ---------------- scan phase B: add block offsets, seed cursor ----------------
__global__ __launch_bounds__(1024) void k_scan_b(int* __restrict__ rowptr,
                                                 int* __restrict__ cursor,
                                                 const int* __restrict__ bsum,
                                                 int N, int nb) {
    __shared__ int s_off;
    if (threadIdx.x == 0) {
        int o = 0;
        for (int b = 0; b < (int)blockIdx.x; ++b) o += bsum[b];
        s_off = o;
        if ((int)blockIdx.x == nb - 1) rowptr[N] = o + bsum[nb - 1];
    }
    __syncthreads();
    const int off = s_off;
    const int i = blockIdx.x * 4096 + threadIdx.x * 4;
    if (i + 3 < N) {
        int4 r = *reinterpret_cast<const int4*>(&rowptr[i]);
        r.x += off; r.y += off; r.z += off; r.w += off;
        *reinterpret_cast<int4*>(&rowptr[i]) = r;
        *reinterpret_cast<int4*>(&cursor[i]) = r;
    } else {
        #pragma unroll
        for (int k = 0; k < 4; ++k) {
            int ii = i + k;
            if (ii < N) {
                int r = rowptr[ii] + off;
                rowptr[ii] = r;
                cursor[ii] = r;
            }
        }
    }
}

// ---------------- segmented CSR fill ----------------
__global__ __launch_bounds__(256) void k_fill(const int* __restrict__ src,
                                              const int* __restrict__ dst,
                                              int* __restrict__ cursor,
                                              int* __restrict__ csr, int E, int nseg) {
    const int stride = gridDim.x * blockDim.x;
    const int t0 = blockIdx.x * blockDim.x + threadIdx.x;
    for (int seg = 0; seg < nseg; ++seg) {
        const int lo = seg << SEG_SHIFT, hi = lo + (1 << SEG_SHIFT);
        for (int e = t0; e < E; e += stride) {
            int d = __builtin_nontemporal_load(&dst[e]);
            if (d >= lo && d < hi) {
                int p = atomicAdd(&cursor[d], 1);
                csr[p] = __builtin_nontemporal_load(&src[e]);
            }
        }
    }
}

// ---------------- gather-mean aggregation (fp16 in, fp32 accum, fp16 out) ----------------
__device__ __forceinline__ void acc_add(float4& a, int2 raw) {
    __half2 h01 = *reinterpret_cast<const __half2*>(&raw.x);
    __half2 h23 = *reinterpret_cast<const __half2*>(&raw.y);
    float2 f01 = __half22float2(h01);
    float2 f23 = __half22float2(h23);
    a.x += f01.x; a.y += f01.y; a.z += f23.x; a.w += f23.y;
}

__global__ __launch_bounds__(512) void k_agg(const int* __restrict__ rowptr,
                                             const int* __restrict__ csr,
                                             const __half* __restrict__ xh,
                                             __half* __restrict__ agg, int N) {
    int w = (int)((blockIdx.x * 512u + threadIdx.x) >> 6);
    int lane = threadIdx.x & 63;
    if (w >= N) return;
    int s0 = rowptr[w], s1 = rowptr[w + 1];
    const int half = lane >> 5;
    const int c4 = lane & 31;                 // 8B chunk index within row
    const int2* xh2 = reinterpret_cast<const int2*>(xh);
    float4 a0 = make_float4(0.f, 0.f, 0.f, 0.f);
    float4 a1 = make_float4(0.f, 0.f, 0.f, 0.f);
    float4 a2 = make_float4(0.f, 0.f, 0.f, 0.f);
    float4 a3 = make_float4(0.f, 0.f, 0.f, 0.f);

    for (int p = s0; p < s1; p += 64) {
        int m = s1 - p; if (m > 64) m = 64;
        int my = (p + lane < s1) ? csr[p + lane] : 0;
        int j = 0;
        for (; j + 15 < m; j += 16) {
            int r0 = __shfl(my, j +      half);
            int r1 = __shfl(my, j + 2  + half);
            int r2 = __shfl(my, j + 4  + half);
            int r3 = __shfl(my, j + 6  + half);
            int r4 = __shfl(my, j + 8  + half);
            int r5 = __shfl(my, j + 10 + half);
            int r6 = __shfl(my, j + 12 + half);
            int r7 = __shfl(my, j + 14 + half);
            int2 v0 = xh2[(size_t)r0 * 32 + c4];
            int2 v1 = xh2[(size_t)r1 * 32 + c4];
            int2 v2 = xh2[(size_t)r2 * 32 + c4];
            int2 v3 = xh2[(size_t)r3 * 32 + c4];
            int2 v4 = xh2[(size_t)r4 * 32 + c4];
            int2 v5 = xh2[(size_t)r5 * 32 + c4];
            int2 v6 = xh2[(size_t)r6 * 32 + c4];
            int2 v7 = xh2[(size_t)r7 * 32 + c4];
            acc_add(a0, v0); acc_add(a1, v1); acc_add(a2, v2); acc_add(a3, v3);
            acc_add(a0, v4); acc_add(a1, v5); acc_add(a2, v6); acc_add(a3, v7);
        }
        for (; j + 7 < m; j += 8) {
            int r0 = __shfl(my, j +     half);
            int r1 = __shfl(my, j + 2 + half);
            int r2 = __shfl(my, j + 4 + half);
            int r3 = __shfl(my, j + 6 + half);
            int2 v0 = xh2[(size_t)r0 * 32 + c4];
            int2 v1 = xh2[(size_t)r1 * 32 + c4];
            int2 v2 = xh2[(size_t)r2 * 32 + c4];
            int2 v3 = xh2[(size_t)r3 * 32 + c4];
            acc_add(a0, v0); acc_add(a1, v1); acc_add(a2, v2); acc_add(a3, v3);
        }
        for (; j + 1 < m; j += 2) {
            int r0 = __shfl(my, j + half);
            int2 v0 = xh2[(size_t)r0 * 32 + c4];
            acc_add(a0, v0);
        }
        if (j < m) {
            int r0 = __shfl(my, j);
            int2 v0 = xh2[(size_t)r0 * 32 + c4];
            if (half == 0) acc_add(a0, v0);
        }
    }

    float4 s;
    s.x = (a0.x + a1.x) + (a2.x + a3.x);
    s.y = (a0.y + a1.y) + (a2.y + a3.y);
    s.z = (a0.z + a1.z) + (a2.z + a3.z);
    s.w = (a0.w + a1.w) + (a2.w + a3.w);
    s.x += __shfl_xor(s.x, 32);
    s.y += __shfl_xor(s.y, 32);
    s.z += __shfl_xor(s.z, 32);
    s.w += __shfl_xor(s.w, 32);

    float inv = 1.0f / fmaxf((float)(s1 - s0), 1.0f);
    if (half == 0) {
        __half2 p01 = __floats2half2_rn(s.x * inv, s.y * inv);
        __half2 p23 = __floats2half2_rn(s.z * inv, s.w * inv);
        nint2 o;
        o.x = *reinterpret_cast<int*>(&p01);
        o.y = *reinterpret_cast<int*>(&p23);
        __builtin_nontemporal_store(o, reinterpret_cast<nint2*>(agg) + (size_t)w * 32 + c4);
    }
}

// ---------------- MFMA fused-layer GEMM ----------------
// out = act( A0@W0^T + A1@W1^T + bias ),  A fp16 [N][128], W fp16 [128][128].
// 256 thr = 4 waves; block tile 64 rows x 128 cols; wave tile 16 x 128.
template <bool RELU, bool OUT_HALF>
__global__ __launch_bounds__(256) void k_mfma2(
    const _Float16* __restrict__ A0, const _Float16* __restrict__ A1,
    const _Float16* __restrict__ W0h, const _Float16* __restrict__ W1h,
    const float* __restrict__ bias,
    float* __restrict__ outF, _Float16* __restrict__ outH, int N)
{
    const int wv = threadIdx.x >> 6;
    const int l  = threadIdx.x & 63;
    const int lr = l & 15;
    const int lk = (l >> 4) * 8;
    const int m0 = blockIdx.x * 64 + wv * 16;

    int arow = m0 + lr; if (arow >= N) arow = N - 1;

    f32x4 zero = {0.f, 0.f, 0.f, 0.f};
    f32x4 acc[8];
    #pragma unroll
    for (int g = 0; g < 8; ++g) acc[g] = zero;

    #pragma unroll
    for (int mat = 0; mat < 2; ++mat) {
        const _Float16* Ap = (mat ? A1 : A0) + (size_t)arow * D + lk;
        const _Float16* Wp = (mat ? W1h : W0h) + (size_t)lr * D + lk;
        #pragma unroll
        for (int kc = 0; kc < D; kc += 32) {
            f16x8 a = *reinterpret_cast<const f16x8*>(Ap + kc);
            #pragma unroll
            for (int g = 0; g < 8; ++g) {
                f16x8 b = *reinterpret_cast<const f16x8*>(Wp + g * 16 * D + kc);
                acc[g] = __builtin_amdgcn_mfma_f32_16x16x32_f16(a, b, acc[g], 0, 0, 0);
            }
        }
    }

    float bia[8];
    #pragma unroll
    for (int g = 0; g < 8; ++g) bia[g] = bias[g * 16 + lr];

    const int rbase = m0 + (l >> 4) * 4;
    #pragma unroll
    for (int r = 0; r < 4; ++r) {
        int row = rbase + r;
        if (row < N) {
            #pragma unroll
            for (int g = 0; g < 8; ++g) {
                float v = acc[g][r] + bia[g];
                if (RELU) v = fmaxf(v, 0.0f);
                int col = g * 16 + lr;
                if (OUT_HALF) outH[(size_t)row * D + col] = (_Float16)v;
                else __builtin_nontemporal_store(v, &outF[(size_t)row * D + col]);
            }
        }
    }
}

// ---------------- MFMA dual-head GEMM: W staged as fp16 in LDS ----------------
// Two passes (Wv then Wt); A fragments converted once and held in regs.
#define WPITCH 136
__global__ __launch_bounds__(256) void k_head16(
    const float* __restrict__ h,
    const float* __restrict__ Wv, const float* __restrict__ bv,
    const float* __restrict__ Wt, const float* __restrict__ bt,
    float* __restrict__ xv, float* __restrict__ xt, int N)
{
    __shared__ _Float16 sW[128 * WPITCH];   // 34.8 KB

    const int tid = threadIdx.x;
    const int wv_ = tid >> 6;
    const int l  = tid & 63;
    const int lr = l & 15;
    const int lk = (l >> 4) * 8;
    const int m0 = blockIdx.x * 64 + wv_ * 16;

    int arow = m0 + lr; if (arow >= N) arow = N - 1;

    // A fragments: fp32 -> fp16 once, held in 16 VGPRs
    f16x8 af[4];
    const float* Ap = h + (size_t)arow * D + lk;
    #pragma unroll
    for (int kc4 = 0; kc4 < 4; ++kc4) {
        float4 a0 = *reinterpret_cast<const float4*>(Ap + kc4 * 32);
        float4 a1 = *reinterpret_cast<const float4*>(Ap + kc4 * 32 + 4);
        f16x8 a;
        a[0] = (_Float16)a0.x; a[1] = (_Float16)a0.y;
        a[2] = (_Float16)a0.z; a[3] = (_Float16)a0.w;
        a[4] = (_Float16)a1.x; a[5] = (_Float16)a1.y;
        a[6] = (_Float16)a1.z; a[7] = (_Float16)a1.w;
        af[kc4] = a;
    }

    f32x4 zero = {0.f, 0.f, 0.f, 0.f};
    f32x4 accv[8], acct[8];
    #pragma unroll
    for (int g = 0; g < 8; ++g) { accv[g] = zero; acct[g] = zero; }

    // ---- pass 0: Wv ----
    #pragma unroll
    for (int it = 0; it < 8; ++it) {
        int idx = it * 256 + tid;               // 2048 chunks of 8 elems
        int row = idx >> 4, kq = idx & 15;
        float4 v0 = *reinterpret_cast<const float4*>(&Wv[row * D + kq * 8]);
        float4 v1 = *reinterpret_cast<const float4*>(&Wv[row * D + kq * 8 + 4]);
        _Float16* d = &sW[row * WPITCH + kq * 8];
        d[0] = (_Float16)v0.x; d[1] = (_Float16)v0.y;
        d[2] = (_Float16)v0.z; d[3] = (_Float16)v0.w;
        d[4] = (_Float16)v1.x; d[5] = (_Float16)v1.y;
        d[6] = (_Float16)v1.z; d[7] = (_Float16)v1.w;
    }
    __syncthreads();
    #pragma unroll
    for (int kc4 = 0; kc4 < 4; ++kc4) {
        #pragma unroll
        for (int g = 0; g < 8; ++g) {
            f16x8 b = *reinterpret_cast<const f16x8*>(
                &sW[(g * 16 + lr) * WPITCH + kc4 * 32 + lk]);
            accv[g] = __builtin_amdgcn_mfma_f32_16x16x32_f16(af[kc4], b, accv[g], 0, 0, 0);
        }
    }
    __syncthreads();

    // ---- pass 1: Wt ----
    #pragma unroll
    for (int it = 0; it < 8; ++it) {
        int idx = it * 256 + tid;
        int row = idx >> 4, kq = idx & 15;
        float4 v0 = *reinterpret_cast<const float4*>(&Wt[row * D + kq * 8]);
        float4 v1 = *reinterpret_cast<const float4*>(&Wt[row * D + kq * 8 + 4]);
        _Float16* d = &sW[row * WPITCH + kq * 8];
        d[0] = (_Float16)v0.x; d[1] = (_Float16)v0.y;
        d[2] = (_Float16)v0.z; d[3] = (_Float16)v0.w;
        d[4] = (_Float16)v1.x; d[5] = (_Float16)v1.y;
        d[6] = (_Float16)v1.z; d[7] = (_Float16)v1.w;
    }
    __syncthreads();
    #pragma unroll
    for (int kc4 = 0; kc4 < 4; ++kc4) {
        #pragma unroll
        for (int g = 0; g < 8; ++g) {
            f16x8 b = *reinterpret_cast<const f16x8*>(
                &sW[(g * 16 + lr) * WPITCH + kc4 * 32 + lk]);
            acct[g] = __builtin_amdgcn_mfma_f32_16x16x32_f16(af[kc4], b, acct[g], 0, 0, 0);
        }
    }

    float bvv[8], btt[8];
    #pragma unroll
    for (int g = 0; g < 8; ++g) {
        bvv[g] = bv[g * 16 + lr];
        btt[g] = bt[g * 16 + lr];
    }

    const int rbase = m0 + (l >> 4) * 4;
    #pragma unroll
    for (int r = 0; r < 4; ++r) {
        int row = rbase + r;
        if (row < N) {
            #pragma unroll
            for (int g = 0; g < 8; ++g) {
                int col = g * 16 + lr;
                float v = fmaxf(accv[g][r] + bvv[g], 0.0f);
                float t = fmaxf(acct[g][r] + btt[g], 0.0f);
                __builtin_nontemporal_store(v, &xv[(size_t)row * D + col]);
                __builtin_nontemporal_store(t, &xt[(size_t)row * D + col]);
            }
        }
    }
}

extern "C" void kernel_launch(void* const* d_in, const int* in_sizes, int n_in,
                              void* d_out, int out_size, void* d_ws, size_t ws_size,
                              hipStream_t stream) {
    const float* x   = (const float*)d_in[0];
    const int*   ei  = (const int*)d_in[1];
    const float* Wl0 = (const float*)d_in[2];
    const float* bl0 = (const float*)d_in[3];
    const float* Wr0 = (const float*)d_in[4];
    const float* Wl1 = (const float*)d_in[5];
    const float* bl1 = (const float*)d_in[6];
    const float* Wr1 = (const float*)d_in[7];
    const float* Wv  = (const float*)d_in[8];
    const float* bv  = (const float*)d_in[9];
    const float* Wt  = (const float*)d_in[10];
    const float* bt  = (const float*)d_in[11];

    const int N = in_sizes[0] / D;       // 100000
    const int E = in_sizes[1] / 2;       // 1600000
    const int* srcv = ei;
    const int* dstv = ei + E;

    float* out = (float*)d_out;
    const size_t nd = (size_t)N * D;
    float* h   = out;                    // final output 0
    float* xvp = out + nd;               // final output 1 (x_vision)
    float* xtp = out + 2 * nd;           // final output 2 (x_text)

    // Scratch placement with verified lifetimes (all inside out; no d_ws needed):
    //  h  region: xh (fp16, 25.6MB)          — dead before gemm1 writes h
    //  xv region: h1h (25.6MB) + Wh4 (128KB) — dead before k_head16 writes xv
    //  xt region: ints (7.6MB) + aggh (25.6) — dead before k_head16 writes xt
    __half*    xh   = (__half*)h;
    __half*    h1h  = (__half*)xvp;
    _Float16*  Wh4  = (_Float16*)((char*)xvp + nd * sizeof(__half));
    _Float16*  Wl0h = Wh4;
    _Float16*  Wr0h = Wh4 + 16384;
    _Float16*  Wl1h = Wh4 + 32768;
    _Float16*  Wr1h = Wh4 + 49152;

    const int nb   = (N + 4095) / 4096;
    const int nseg = (N + (1 << SEG_SHIFT) - 1) >> SEG_SHIFT;
    size_t intWords = (size_t)(3 * N + 1) + (size_t)E + (size_t)nb;
    size_t ints_pad = (intWords * sizeof(int) + 15) & ~(size_t)15;

    int* wsI    = (int*)xtp;
    int* degI   = wsI;
    int* rowptr = wsI + N;
    int* cursor = wsI + 2 * N + 1;
    int* csr    = wsI + 3 * N + 1;
    int* bsum   = wsI + 3 * N + 1 + E;
    __half* aggh = (__half*)((char*)xtp + ints_pad);

    // ---- CSR build ----
    (void)hipMemsetAsync(degI, 0, (size_t)N * sizeof(int), stream);
    k_deg <<<2048, 256, 0, stream>>>(dstv, degI, E, nseg);
    k_scan_a<<<nb, 1024, 0, stream>>>(degI, rowptr, bsum, N);
    k_scan_b<<<nb, 1024, 0, stream>>>(rowptr, cursor, bsum, N, nb);
    k_fill<<<2048, 256, 0, stream>>>(srcv, dstv, cursor, csr, E, nseg);

    const int agg_blocks = (int)(((size_t)N * 64 + 511) / 512);
    const int mblocks    = (N + 63) / 64;
    const int n8         = (int)(nd / 8);

    // ---- conversions ----
    k_cvt <<<2048, 256, 0, stream>>>(x, xh, n8);
    k_cvtw<<<32, 256, 0, stream>>>(Wl0, Wr0, Wl1, Wr1, Wh4);

    // ---- layer 0: h1 = relu(agg(x)@Wl0^T + bl0 + x@Wr0^T), emitted fp16 ----
    k_agg<<<agg_blocks, 512, 0, stream>>>(rowptr, csr, xh, aggh, N);
    k_mfma2<true, true><<<mblocks, 256, 0, stream>>>(
        (const _Float16*)aggh, (const _Float16*)xh, Wl0h, Wr0h, bl0,
        nullptr, (_Float16*)h1h, N);

    // ---- layer 1: h = agg(h1)@Wl1^T + bl1 + h1@Wr1^T (fp32 final) ----
    k_agg<<<agg_blocks, 512, 0, stream>>>(rowptr, csr, h1h, aggh, N);
    k_mfma2<false, false><<<mblocks, 256, 0, stream>>>(
        (const _Float16*)aggh, (const _Float16*)h1h, Wl1h, Wr1h, bl1,
        h, nullptr, N);

    // ---- heads: xv = relu(h@Wv^T+bv), xt = relu(h@Wt^T+bt) ----
    k_head16<<<mblocks, 256, 0, stream>>>(h, Wv, bv, Wt, bt, xvp, xtp, N);
}

// Round 11
// 452.902 us; speedup vs baseline: 4.0330x; 1.0565x over previous
//
#include <hip/hip_runtime.h>
#include <hip/hip_fp16.h>

#define D 128

typedef _Float16 f16x8 __attribute__((ext_vector_type(8)));
typedef float    f32x4 __attribute__((ext_vector_type(4)));
typedef int      nint2 __attribute__((ext_vector_type(2)));

// ---------------- fp32 -> fp16 cast (vectorized) ----------------
__global__ __launch_bounds__(256) void k_cvt(const float* __restrict__ in,
                                             __half* __restrict__ out, int n8) {
    int i = blockIdx.x * 256 + threadIdx.x;
    const int stride = gridDim.x * 256;
    for (; i < n8; i += stride) {
        float4 a = reinterpret_cast<const float4*>(in)[(size_t)i * 2];
        float4 b = reinterpret_cast<const float4*>(in)[(size_t)i * 2 + 1];
        __half2 h0 = __floats2half2_rn(a.x, a.y);
        __half2 h1 = __floats2half2_rn(a.z, a.w);
        __half2 h2 = __floats2half2_rn(b.x, b.y);
        __half2 h3 = __floats2half2_rn(b.z, b.w);
        int4 o;
        o.x = *reinterpret_cast<int*>(&h0);
        o.y = *reinterpret_cast<int*>(&h1);
        o.z = *reinterpret_cast<int*>(&h2);
        o.w = *reinterpret_cast<int*>(&h3);
        reinterpret_cast<int4*>(out)[i] = o;
    }
}

// ---------------- 4 weight matrices fp32 -> fp16 ----------------
__global__ __launch_bounds__(256) void k_cvtw(const float* __restrict__ W0,
                                              const float* __restrict__ W1,
                                              const float* __restrict__ W2,
                                              const float* __restrict__ W3,
                                              _Float16* __restrict__ out) {
    int idx = blockIdx.x * 256 + threadIdx.x;      // 8192 chunks of 8 elems
    if (idx >= 8192) return;
    int mat = idx >> 11;                            // 2048 chunks per matrix
    int off = idx & 2047;
    const float* s = (mat == 0) ? W0 : (mat == 1) ? W1 : (mat == 2) ? W2 : W3;
    float4 a = reinterpret_cast<const float4*>(s)[(size_t)off * 2];
    float4 b = reinterpret_cast<const float4*>(s)[(size_t)off * 2 + 1];
    __half2 h0 = __floats2half2_rn(a.x, a.y);
    __half2 h1 = __floats2half2_rn(a.z, a.w);
    __half2 h2 = __floats2half2_rn(b.x, b.y);
    __half2 h3 = __floats2half2_rn(b.z, b.w);
    int4 o;
    o.x = *reinterpret_cast<int*>(&h0);
    o.y = *reinterpret_cast<int*>(&h1);
    o.z = *reinterpret_cast<int*>(&h2);
    o.w = *reinterpret_cast<int*>(&h3);
    reinterpret_cast<int4*>(out)[idx] = o;
}

// ---------------- XCD-partitioned degree histogram ----------------
// Blocks with bid%8==k own dst segment k (bid%8 ~ XCD id under round-robin
// dispatch) -> deg lines for a segment live in ONE XCD's L2 -> no cross-XCD
// line ping-pong on the atomic scatter.
__global__ __launch_bounds__(256) void k_deg(const int* __restrict__ dst,
                                             int* __restrict__ deg, int E,
                                             int segSize, int N) {
    const int grp = blockIdx.x & 7;
    const int lo = grp * segSize;
    int hi = lo + segSize; if (hi > N) hi = N;
    const int nthr = (gridDim.x >> 3) * blockDim.x;
    const int t0 = (blockIdx.x >> 3) * blockDim.x + threadIdx.x;
    for (int e = t0; e < E; e += nthr) {
        int d = __builtin_nontemporal_load(&dst[e]);
        if (d >= lo && d < hi) atomicAdd(&deg[d], 1);
    }
}

// ---------------- multi-block exclusive scan, phase A ----------------
__global__ __launch_bounds__(1024) void k_scan_a(const int* __restrict__ deg,
                                                 int* __restrict__ rowptr,
                                                 int* __restrict__ bsum, int N) {
    __shared__ int wsum[16];
    __shared__ int wscan[16];
    const int tid = threadIdx.x, lane = tid & 63, wid = tid >> 6;
    const int i = blockIdx.x * 4096 + tid * 4;
    int4 v = *reinterpret_cast<const int4*>(&deg[i]);
    int v0 = (i     < N) ? v.x : 0;
    int v1 = (i + 1 < N) ? v.y : 0;
    int v2 = (i + 2 < N) ? v.z : 0;
    int v3 = (i + 3 < N) ? v.w : 0;
    const int t = v0 + v1 + v2 + v3;
    int x = t;
    #pragma unroll
    for (int off = 1; off < 64; off <<= 1) {
        int u = __shfl_up(x, off);
        if (lane >= off) x += u;
    }
    if (lane == 63) wsum[wid] = x;
    __syncthreads();
    if (wid == 0) {
        int s = (lane < 16) ? wsum[lane] : 0;
        #pragma unroll
        for (int off = 1; off < 16; off <<= 1) {
            int u = __shfl_up(s, off);
            if (lane >= off) s += u;
        }
        if (lane < 16) wscan[lane] = s;
    }
    __syncthreads();
    int excl = x - t + ((wid > 0) ? wscan[wid - 1] : 0);
    if (i     < N) rowptr[i]     = excl;
    if (i + 1 < N) rowptr[i + 1] = excl + v0;
    if (i + 2 < N) rowptr[i + 2] = excl + v0 + v1;
    if (i + 3 < N) rowptr[i + 3] = excl + v0 + v1 + v2;
    if (tid == 0) bsum[blockIdx.x] = wscan[15];
}

// ---------------- scan phase B: add block offsets, seed cursor ----------------
__global__ __launch_bounds__(1024) void k_scan_b(int* __restrict__ rowptr,
                                                 int* __restrict__ cursor,
                                                 const int* __restrict__ bsum,
                                                 int N, int nb) {
    __shared__ int s_off;
    if (threadIdx.x == 0) {
        int o = 0;
        for (int b = 0; b < (int)blockIdx.x; ++b) o += bsum[b];
        s_off = o;
        if ((int)blockIdx.x == nb - 1) rowptr[N] = o + bsum[nb - 1];
    }
    __syncthreads();
    const int off = s_off;
    const int i = blockIdx.x * 4096 + threadIdx.x * 4;
    if (i + 3 < N) {
        int4 r = *reinterpret_cast<const int4*>(&rowptr[i]);
        r.x += off; r.y += off; r.z += off; r.w += off;
        *reinterpret_cast<int4*>(&rowptr[i]) = r;
        *reinterpret_cast<int4*>(&cursor[i]) = r;
    } else {
        #pragma unroll
        for (int k = 0; k < 4; ++k) {
            int ii = i + k;
            if (ii < N) {
                int r = rowptr[ii] + off;
                rowptr[ii] = r;
                cursor[ii] = r;
            }
        }
    }
}

// ---------------- XCD-partitioned CSR fill ----------------
// Same ownership scheme: csr/cursor lines of segment k written only by the
// blocks (one XCD) owning that segment -> partial-line stores merge in L2.
__global__ __launch_bounds__(256) void k_fill(const int* __restrict__ src,
                                              const int* __restrict__ dst,
                                              int* __restrict__ cursor,
                                              int* __restrict__ csr, int E,
                                              int segSize, int N) {
    const int grp = blockIdx.x & 7;
    const int lo = grp * segSize;
    int hi = lo + segSize; if (hi > N) hi = N;
    const int nthr = (gridDim.x >> 3) * blockDim.x;
    const int t0 = (blockIdx.x >> 3) * blockDim.x + threadIdx.x;
    for (int e = t0; e < E; e += nthr) {
        int d = __builtin_nontemporal_load(&dst[e]);
        if (d >= lo && d < hi) {
            int p = atomicAdd(&cursor[d], 1);
            csr[p] = __builtin_nontemporal_load(&src[e]);
        }
    }
}

// ---------------- gather-mean aggregation (fp16 in, fp32 accum, fp16 out) ----------------
__device__ __forceinline__ void acc_add(float4& a, int2 raw) {
    __half2 h01 = *reinterpret_cast<const __half2*>(&raw.x);
    __half2 h23 = *reinterpret_cast<const __half2*>(&raw.y);
    float2 f01 = __half22float2(h01);
    float2 f23 = __half22float2(h23);
    a.x += f01.x; a.y += f01.y; a.z += f23.x; a.w += f23.y;
}

__global__ __launch_bounds__(512) void k_agg(const int* __restrict__ rowptr,
                                             const int* __restrict__ csr,
                                             const __half* __restrict__ xh,
                                             __half* __restrict__ agg, int N) {
    int w = (int)((blockIdx.x * 512u + threadIdx.x) >> 6);
    int lane = threadIdx.x & 63;
    if (w >= N) return;
    int s0 = rowptr[w], s1 = rowptr[w + 1];
    const int half = lane >> 5;
    const int c4 = lane & 31;                 // 8B chunk index within row
    const int2* xh2 = reinterpret_cast<const int2*>(xh);
    float4 a0 = make_float4(0.f, 0.f, 0.f, 0.f);
    float4 a1 = make_float4(0.f, 0.f, 0.f, 0.f);
    float4 a2 = make_float4(0.f, 0.f, 0.f, 0.f);
    float4 a3 = make_float4(0.f, 0.f, 0.f, 0.f);

    for (int p = s0; p < s1; p += 64) {
        int m = s1 - p; if (m > 64) m = 64;
        int my = (p + lane < s1) ? csr[p + lane] : 0;
        int j = 0;
        for (; j + 15 < m; j += 16) {
            int r0 = __shfl(my, j +      half);
            int r1 = __shfl(my, j + 2  + half);
            int r2 = __shfl(my, j + 4  + half);
            int r3 = __shfl(my, j + 6  + half);
            int r4 = __shfl(my, j + 8  + half);
            int r5 = __shfl(my, j + 10 + half);
            int r6 = __shfl(my, j + 12 + half);
            int r7 = __shfl(my, j + 14 + half);
            int2 v0 = xh2[(size_t)r0 * 32 + c4];
            int2 v1 = xh2[(size_t)r1 * 32 + c4];
            int2 v2 = xh2[(size_t)r2 * 32 + c4];
            int2 v3 = xh2[(size_t)r3 * 32 + c4];
            int2 v4 = xh2[(size_t)r4 * 32 + c4];
            int2 v5 = xh2[(size_t)r5 * 32 + c4];
            int2 v6 = xh2[(size_t)r6 * 32 + c4];
            int2 v7 = xh2[(size_t)r7 * 32 + c4];
            acc_add(a0, v0); acc_add(a1, v1); acc_add(a2, v2); acc_add(a3, v3);
            acc_add(a0, v4); acc_add(a1, v5); acc_add(a2, v6); acc_add(a3, v7);
        }
        for (; j + 7 < m; j += 8) {
            int r0 = __shfl(my, j +     half);
            int r1 = __shfl(my, j + 2 + half);
            int r2 = __shfl(my, j + 4 + half);
            int r3 = __shfl(my, j + 6 + half);
            int2 v0 = xh2[(size_t)r0 * 32 + c4];
            int2 v1 = xh2[(size_t)r1 * 32 + c4];
            int2 v2 = xh2[(size_t)r2 * 32 + c4];
            int2 v3 = xh2[(size_t)r3 * 32 + c4];
            acc_add(a0, v0); acc_add(a1, v1); acc_add(a2, v2); acc_add(a3, v3);
        }
        for (; j + 1 < m; j += 2) {
            int r0 = __shfl(my, j + half);
            int2 v0 = xh2[(size_t)r0 * 32 + c4];
            acc_add(a0, v0);
        }
        if (j < m) {
            int r0 = __shfl(my, j);
            int2 v0 = xh2[(size_t)r0 * 32 + c4];
            if (half == 0) acc_add(a0, v0);
        }
    }

    float4 s;
    s.x = (a0.x + a1.x) + (a2.x + a3.x);
    s.y = (a0.y + a1.y) + (a2.y + a3.y);
    s.z = (a0.z + a1.z) + (a2.z + a3.z);
    s.w = (a0.w + a1.w) + (a2.w + a3.w);
    s.x += __shfl_xor(s.x, 32);
    s.y += __shfl_xor(s.y, 32);
    s.z += __shfl_xor(s.z, 32);
    s.w += __shfl_xor(s.w, 32);

    float inv = 1.0f / fmaxf((float)(s1 - s0), 1.0f);
    if (half == 0) {
        __half2 p01 = __floats2half2_rn(s.x * inv, s.y * inv);
        __half2 p23 = __floats2half2_rn(s.z * inv, s.w * inv);
        nint2 o;
        o.x = *reinterpret_cast<int*>(&p01);
        o.y = *reinterpret_cast<int*>(&p23);
        __builtin_nontemporal_store(o, reinterpret_cast<nint2*>(agg) + (size_t)w * 32 + c4);
    }
}

// ---------------- MFMA fused-layer GEMM ----------------
template <bool RELU, bool OUT_HALF>
__global__ __launch_bounds__(256) void k_mfma2(
    const _Float16* __restrict__ A0, const _Float16* __restrict__ A1,
    const _Float16* __restrict__ W0h, const _Float16* __restrict__ W1h,
    const float* __restrict__ bias,
    float* __restrict__ outF, _Float16* __restrict__ outH, int N)
{
    const int wv = threadIdx.x >> 6;
    const int l  = threadIdx.x & 63;
    const int lr = l & 15;
    const int lk = (l >> 4) * 8;
    const int m0 = blockIdx.x * 64 + wv * 16;

    int arow = m0 + lr; if (arow >= N) arow = N - 1;

    f32x4 zero = {0.f, 0.f, 0.f, 0.f};
    f32x4 acc[8];
    #pragma unroll
    for (int g = 0; g < 8; ++g) acc[g] = zero;

    #pragma unroll
    for (int mat = 0; mat < 2; ++mat) {
        const _Float16* Ap = (mat ? A1 : A0) + (size_t)arow * D + lk;
        const _Float16* Wp = (mat ? W1h : W0h) + (size_t)lr * D + lk;
        #pragma unroll
        for (int kc = 0; kc < D; kc += 32) {
            f16x8 a = *reinterpret_cast<const f16x8*>(Ap + kc);
            #pragma unroll
            for (int g = 0; g < 8; ++g) {
                f16x8 b = *reinterpret_cast<const f16x8*>(Wp + g * 16 * D + kc);
                acc[g] = __builtin_amdgcn_mfma_f32_16x16x32_f16(a, b, acc[g], 0, 0, 0);
            }
        }
    }

    float bia[8];
    #pragma unroll
    for (int g = 0; g < 8; ++g) bia[g] = bias[g * 16 + lr];

    const int rbase = m0 + (l >> 4) * 4;
    #pragma unroll
    for (int r = 0; r < 4; ++r) {
        int row = rbase + r;
        if (row < N) {
            #pragma unroll
            for (int g = 0; g < 8; ++g) {
                float v = acc[g][r] + bia[g];
                if (RELU) v = fmaxf(v, 0.0f);
                int col = g * 16 + lr;
                if (OUT_HALF) outH[(size_t)row * D + col] = (_Float16)v;
                else __builtin_nontemporal_store(v, &outF[(size_t)row * D + col]);
            }
        }
    }
}

// ---------------- MFMA dual-head GEMM: W staged as fp16 in LDS ----------------
#define WPITCH 136
__global__ __launch_bounds__(256) void k_head16(
    const float* __restrict__ h,
    const float* __restrict__ Wv, const float* __restrict__ bv,
    const float* __restrict__ Wt, const float* __restrict__ bt,
    float* __restrict__ xv, float* __restrict__ xt, int N)
{
    __shared__ _Float16 sW[128 * WPITCH];   // 34.8 KB

    const int tid = threadIdx.x;
    const int wv_ = tid >> 6;
    const int l  = tid & 63;
    const int lr = l & 15;
    const int lk = (l >> 4) * 8;
    const int m0 = blockIdx.x * 64 + wv_ * 16;

    int arow = m0 + lr; if (arow >= N) arow = N - 1;

    f16x8 af[4];
    const float* Ap = h + (size_t)arow * D + lk;
    #pragma unroll
    for (int kc4 = 0; kc4 < 4; ++kc4) {
        float4 a0 = *reinterpret_cast<const float4*>(Ap + kc4 * 32);
        float4 a1 = *reinterpret_cast<const float4*>(Ap + kc4 * 32 + 4);
        f16x8 a;
        a[0] = (_Float16)a0.x; a[1] = (_Float16)a0.y;
        a[2] = (_Float16)a0.z; a[3] = (_Float16)a0.w;
        a[4] = (_Float16)a1.x; a[5] = (_Float16)a1.y;
        a[6] = (_Float16)a1.z; a[7] = (_Float16)a1.w;
        af[kc4] = a;
    }

    f32x4 zero = {0.f, 0.f, 0.f, 0.f};
    f32x4 accv[8], acct[8];
    #pragma unroll
    for (int g = 0; g < 8; ++g) { accv[g] = zero; acct[g] = zero; }

    // ---- pass 0: Wv ----
    #pragma unroll
    for (int it = 0; it < 8; ++it) {
        int idx = it * 256 + tid;
        int row = idx >> 4, kq = idx & 15;
        float4 v0 = *reinterpret_cast<const float4*>(&Wv[row * D + kq * 8]);
        float4 v1 = *reinterpret_cast<const float4*>(&Wv[row * D + kq * 8 + 4]);
        _Float16* d = &sW[row * WPITCH + kq * 8];
        d[0] = (_Float16)v0.x; d[1] = (_Float16)v0.y;
        d[2] = (_Float16)v0.z; d[3] = (_Float16)v0.w;
        d[4] = (_Float16)v1.x; d[5] = (_Float16)v1.y;
        d[6] = (_Float16)v1.z; d[7] = (_Float16)v1.w;
    }
    __syncthreads();
    #pragma unroll
    for (int kc4 = 0; kc4 < 4; ++kc4) {
        #pragma unroll
        for (int g = 0; g < 8; ++g) {
            f16x8 b = *reinterpret_cast<const f16x8*>(
                &sW[(g * 16 + lr) * WPITCH + kc4 * 32 + lk]);
            accv[g] = __builtin_amdgcn_mfma_f32_16x16x32_f16(af[kc4], b, accv[g], 0, 0, 0);
        }
    }
    __syncthreads();

    // ---- pass 1: Wt ----
    #pragma unroll
    for (int it = 0; it < 8; ++it) {
        int idx = it * 256 + tid;
        int row = idx >> 4, kq = idx & 15;
        float4 v0 = *reinterpret_cast<const float4*>(&Wt[row * D + kq * 8]);
        float4 v1 = *reinterpret_cast<const float4*>(&Wt[row * D + kq * 8 + 4]);
        _Float16* d = &sW[row * WPITCH + kq * 8];
        d[0] = (_Float16)v0.x; d[1] = (_Float16)v0.y;
        d[2] = (_Float16)v0.z; d[3] = (_Float16)v0.w;
        d[4] = (_Float16)v1.x; d[5] = (_Float16)v1.y;
        d[6] = (_Float16)v1.z; d[7] = (_Float16)v1.w;
    }
    __syncthreads();
    #pragma unroll
    for (int kc4 = 0; kc4 < 4; ++kc4) {
        #pragma unroll
        for (int g = 0; g < 8; ++g) {
            f16x8 b = *reinterpret_cast<const f16x8*>(
                &sW[(g * 16 + lr) * WPITCH + kc4 * 32 + lk]);
            acct[g] = __builtin_amdgcn_mfma_f32_16x16x32_f16(af[kc4], b, acct[g], 0, 0, 0);
        }
    }

    float bvv[8], btt[8];
    #pragma unroll
    for (int g = 0; g < 8; ++g) {
        bvv[g] = bv[g * 16 + lr];
        btt[g] = bt[g * 16 + lr];
    }

    const int rbase = m0 + (l >> 4) * 4;
    #pragma unroll
    for (int r = 0; r < 4; ++r) {
        int row = rbase + r;
        if (row < N) {
            #pragma unroll
            for (int g = 0; g < 8; ++g) {
                int col = g * 16 + lr;
                float v = fmaxf(accv[g][r] + bvv[g], 0.0f);
                float t = fmaxf(acct[g][r] + btt[g], 0.0f);
                __builtin_nontemporal_store(v, &xv[(size_t)row * D + col]);
                __builtin_nontemporal_store(t, &xt[(size_t)row * D + col]);
            }
        }
    }
}

extern "C" void kernel_launch(void* const* d_in, const int* in_sizes, int n_in,
                              void* d_out, int out_size, void* d_ws, size_t ws_size,
                              hipStream_t stream) {
    const float* x   = (const float*)d_in[0];
    const int*   ei  = (const int*)d_in[1];
    const float* Wl0 = (const float*)d_in[2];
    const float* bl0 = (const float*)d_in[3];
    const float* Wr0 = (const float*)d_in[4];
    const float* Wl1 = (const float*)d_in[5];
    const float* bl1 = (const float*)d_in[6];
    const float* Wr1 = (const float*)d_in[7];
    const float* Wv  = (const float*)d_in[8];
    const float* bv  = (const float*)d_in[9];
    const float* Wt  = (const float*)d_in[10];
    const float* bt  = (const float*)d_in[11];

    const int N = in_sizes[0] / D;       // 100000
    const int E = in_sizes[1] / 2;       // 1600000
    const int* srcv = ei;
    const int* dstv = ei + E;

    float* out = (float*)d_out;
    const size_t nd = (size_t)N * D;
    float* h   = out;                    // final output 0
    float* xvp = out + nd;               // final output 1 (x_vision)
    float* xtp = out + 2 * nd;           // final output 2 (x_text)

    // Scratch placement with verified lifetimes (all inside out; no d_ws needed):
    //  h  region: xh (fp16, 25.6MB)          — dead before gemm1 writes h
    //  xv region: h1h (25.6MB) + Wh4 (128KB) — dead before k_head16 writes xv
    //  xt region: ints (7.6MB) + aggh (25.6) — dead before k_head16 writes xt
    __half*    xh   = (__half*)h;
    __half*    h1h  = (__half*)xvp;
    _Float16*  Wh4  = (_Float16*)((char*)xvp + nd * sizeof(__half));
    _Float16*  Wl0h = Wh4;
    _Float16*  Wr0h = Wh4 + 16384;
    _Float16*  Wl1h = Wh4 + 32768;
    _Float16*  Wr1h = Wh4 + 49152;

    const int nb      = (N + 4095) / 4096;
    const int segSize = (N + 7) / 8;     // 8 XCD-owned dst segments
    size_t intWords = (size_t)(3 * N + 1) + (size_t)E + (size_t)nb;
    size_t ints_pad = (intWords * sizeof(int) + 15) & ~(size_t)15;

    int* wsI    = (int*)xtp;
    int* degI   = wsI;
    int* rowptr = wsI + N;
    int* cursor = wsI + 2 * N + 1;
    int* csr    = wsI + 3 * N + 1;
    int* bsum   = wsI + 3 * N + 1 + E;
    __half* aggh = (__half*)((char*)xtp + ints_pad);

    // ---- CSR build ----
    (void)hipMemsetAsync(degI, 0, (size_t)N * sizeof(int), stream);
    k_deg <<<2048, 256, 0, stream>>>(dstv, degI, E, segSize, N);
    k_scan_a<<<nb, 1024, 0, stream>>>(degI, rowptr, bsum, N);
    k_scan_b<<<nb, 1024, 0, stream>>>(rowptr, cursor, bsum, N, nb);
    k_fill<<<2048, 256, 0, stream>>>(srcv, dstv, cursor, csr, E, segSize, N);

    const int agg_blocks = (int)(((size_t)N * 64 + 511) / 512);
    const int mblocks    = (N + 63) / 64;
    const int n8         = (int)(nd / 8);

    // ---- conversions ----
    k_cvt <<<2048, 256, 0, stream>>>(x, xh, n8);
    k_cvtw<<<32, 256, 0, stream>>>(Wl0, Wr0, Wl1, Wr1, Wh4);

    // ---- layer 0: h1 = relu(agg(x)@Wl0^T + bl0 + x@Wr0^T), emitted fp16 ----
    k_agg<<<agg_blocks, 512, 0, stream>>>(rowptr, csr, xh, aggh, N);
    k_mfma2<true, true><<<mblocks, 256, 0, stream>>>(
        (const _Float16*)aggh, (const _Float16*)xh, Wl0h, Wr0h, bl0,
        nullptr, (_Float16*)h1h, N);

    // ---- layer 1: h = agg(h1)@Wl1^T + bl1 + h1@Wr1^T (fp32 final) ----
    k_agg<<<agg_blocks, 512, 0, stream>>>(rowptr, csr, h1h, aggh, N);
    k_mfma2<false, false><<<mblocks, 256, 0, stream>>>(
        (const _Float16*)aggh, (const _Float16*)h1h, Wl1h, Wr1h, bl1,
        h, nullptr, N);

    // ---- heads: xv = relu(h@Wv^T+bv), xt = relu(h@Wt^T+bt) ----
    k_head16<<<mblocks, 256, 0, stream>>>(h, Wv, bv, Wt, bt, xvp, xtp, N);
}